// Round 15
// baseline (103.720 us; speedup 1.0000x reference)
//
#include <hip/hip_runtime.h>
#include <math.h>

// ---------------------------------------------------------------------------
// SpatialProximityHead on MI355X — round 14: full-width grids.
// attn 256 blocks (h, slab, d-half); fcqkv/oprojqkv 384 blocks (prob x
// col-quarter); oprojmlpU 256 blocks (p x col-quarter). 7 dispatches.
// ---------------------------------------------------------------------------

#define NTOK 512
#define HDIM 256
#define DKH  64
#define NHEAD 4
#define TLEN 6
#define WSZ  65536
#define PSTR 520   // attn P_lds ushort stride
#define XPS  264   // LDS panel ushort stride

typedef __attribute__((ext_vector_type(8))) short bf16x8;
typedef __attribute__((ext_vector_type(4))) float f32x4;

__device__ __forceinline__ ushort f2bf(float f)
{
    unsigned u = __builtin_bit_cast(unsigned, f);
    u += 0x7FFFu + ((u >> 16) & 1u);     // RNE
    return (ushort)(u >> 16);
}
__device__ __forceinline__ float bf_lo(unsigned u)
{
    return __builtin_bit_cast(float, u << 16);
}
__device__ __forceinline__ float bf_hi(unsigned u)
{
    return __builtin_bit_cast(float, u & 0xFFFF0000u);
}

struct PKArg {
    const float* w[13];
    const float* pl;
    ushort* wpk;
    float *dist, *dwraw, *inv_cs;
};

// ---------------------------------------------------------------------------
// pack: 0-207 weight 64x64 transpose tiles ([col][k] bf16); 208-215 dist prep.
// ---------------------------------------------------------------------------
__global__ __launch_bounds__(256) void pack_kernel(PKArg p)
{
    __shared__ __align__(16) ushort smu[64 * 72];
    const int bid = blockIdx.x;
    const int t   = threadIdx.x;

    if (bid < 208) {
        const int mat  = bid >> 4;
        const int tile = bid & 15;
        const int k0   = (tile >> 2) * 64;
        const int c0   = (tile & 3) * 64;
        const float* W = p.w[mat];
#pragma unroll
        for (int j = 0; j < 4; ++j) {
            const int i  = t + j * 256;
            const int r  = i >> 4, c4 = i & 15;
            const float4 v4 = *(const float4*)&W[(k0 + r) * HDIM + c0 + c4 * 4];
            smu[(c4 * 4 + 0) * 72 + r] = f2bf(v4.x);
            smu[(c4 * 4 + 1) * 72 + r] = f2bf(v4.y);
            smu[(c4 * 4 + 2) * 72 + r] = f2bf(v4.z);
            smu[(c4 * 4 + 3) * 72 + r] = f2bf(v4.w);
        }
        __syncthreads();
#pragma unroll
        for (int j = 0; j < 2; ++j) {
            const int i  = t + j * 256;
            const int cr = i >> 3, kk = i & 7;
            const uint4 v = *(const uint4*)&smu[cr * 72 + kk * 8];
            *(uint4*)&p.wpk[mat * WSZ + (c0 + cr) * HDIM + k0 + kk * 8] = v;
        }
    } else {
        float* smf = (float*)smu;
        float* qe  = smf;            // [512][3]
        float* red = smf + 1536;     // [4][64]
        const int item = bid - 208;
        for (int i = t; i < 512; i += 256) {
            qe[i * 3 + 0] = p.pl[i * 33 + 30];
            qe[i * 3 + 1] = p.pl[i * 33 + 31];
            qe[i * 3 + 2] = p.pl[i * 33 + 32];
        }
        __syncthreads();
        const int m   = item * 64 + (t & 63);
        const int nch = t >> 6;
        const float kx = p.pl[m * 33 + 0], ky = p.pl[m * 33 + 1], kz = p.pl[m * 33 + 2];
        float cs = 0.f;
        for (int n = nch * 128; n < nch * 128 + 128; ++n) {
            const float dx = kx - qe[n * 3 + 0];
            const float dy = ky - qe[n * 3 + 1];
            const float dz = kz - qe[n * 3 + 2];
            const float dd = sqrtf(dx * dx + dy * dy + dz * dz);
            const float w  = 1.0f / (dd + 0.01f);
            p.dist[n * NTOK + m]  = dd;
            p.dwraw[n * NTOK + m] = w;
            cs += w;
        }
        red[nch * 64 + (t & 63)] = cs;
        __syncthreads();
        if (t < 64)
            p.inv_cs[item * 64 + t] =
                1.0f / (red[t] + red[64 + t] + red[128 + t] + red[192 + t]);
    }
}

// ---------------------------------------------------------------------------
// qkv_one1: one qkv problem, ONE col-group at c0 (8-MFMA chain).
// prob: 0->q16, 1->k16 (row-major), 2->vT16 (transposed).
// ---------------------------------------------------------------------------
__device__ __forceinline__ void qkv_one1(
    const ushort* __restrict__ xpan, const ushort* __restrict__ Wt,
    const float* __restrict__ bb, int prob,
    int slab, int c0, int lr, int lg, int lk,
    ushort* __restrict__ q16, ushort* __restrict__ k16,
    ushort* __restrict__ vT16)
{
    const ushort* Ap = xpan + lr * XPS + lk;
    f32x4 acc = (f32x4){0.f, 0.f, 0.f, 0.f};
#pragma unroll
    for (int ks = 0; ks < 8; ++ks) {
        const bf16x8 a = *(const bf16x8*)&Ap[ks * 32];
        const bf16x8 b = *(const bf16x8*)&Wt[(c0 + lr) * HDIM + ks * 32 + lk];
        acc = __builtin_amdgcn_mfma_f32_16x16x32_bf16(a, b, acc, 0, 0, 0);
    }
    const int col = c0 + lr;
    const float bv2 = bb[col];
    if (prob < 2) {
        ushort* dst = (prob == 0) ? q16 : k16;
#pragma unroll
        for (int rg = 0; rg < 4; ++rg)
            dst[(slab + lg * 4 + rg) * HDIM + col] = f2bf(acc[rg] + bv2);
    } else {
        ushort4 s = {f2bf(acc[0] + bv2), f2bf(acc[1] + bv2),
                     f2bf(acc[2] + bv2), f2bf(acc[3] + bv2)};
        *(ushort4*)&vT16[col * NTOK + slab + lg * 4] = s;
    }
}

// ---------------------------------------------------------------------------
// fcqkv: 384 blocks. p12 = bid>>5 (0..11): prob = p12>>2, qtr = p12&3.
// Phase 1 (replicated x12): fc -> xpan (+ xa f32 if p12==0).
// Phase 2: qkv problem prob, col-group qtr*64 + wv*16.
// ---------------------------------------------------------------------------
__global__ __launch_bounds__(256) void fcqkv(
    const float* __restrict__ qf, const ushort* __restrict__ fcWt,
    const float* __restrict__ fcb,
    const ushort* __restrict__ WqT, const float* __restrict__ bq,
    const ushort* __restrict__ WkT, const float* __restrict__ bk,
    const ushort* __restrict__ WvT, const float* __restrict__ bv,
    float* __restrict__ xa, ushort* __restrict__ q16,
    ushort* __restrict__ k16, ushort* __restrict__ vT16)
{
    __shared__ __align__(16) ushort xpan[16 * XPS];
    const int bid  = blockIdx.x;
    const int p12  = bid >> 5;
    const int slab = (bid & 31) * 16;
    const int t = threadIdx.x;
    const int wv = t >> 6, lane = t & 63;
    const int lr = lane & 15, lg = lane >> 4, lk = lg * 8;
    const int c0 = wv * 64;

    {   // phase 1: fc (replicated)
        f32x4 acc[4];
#pragma unroll
        for (int j = 0; j < 4; ++j) acc[j] = (f32x4){0.f, 0.f, 0.f, 0.f};
        const float* Aq = qf + (slab + lr) * HDIM + lk;
#pragma unroll
        for (int ks = 0; ks < 8; ++ks) {
            const float4 a0 = *(const float4*)&Aq[ks * 32];
            const float4 a1 = *(const float4*)&Aq[ks * 32 + 4];
            bf16x8 a;
            a[0] = (short)f2bf(a0.x); a[1] = (short)f2bf(a0.y);
            a[2] = (short)f2bf(a0.z); a[3] = (short)f2bf(a0.w);
            a[4] = (short)f2bf(a1.x); a[5] = (short)f2bf(a1.y);
            a[6] = (short)f2bf(a1.z); a[7] = (short)f2bf(a1.w);
#pragma unroll
            for (int j = 0; j < 4; ++j) {
                const bf16x8 b = *(const bf16x8*)&fcWt[(c0 + j * 16 + lr) * HDIM + ks * 32 + lk];
                acc[j] = __builtin_amdgcn_mfma_f32_16x16x32_bf16(a, b, acc[j], 0, 0, 0);
            }
        }
#pragma unroll
        for (int j = 0; j < 4; ++j) {
            const int col = c0 + j * 16 + lr;
            const float bbv = fcb[col];
#pragma unroll
            for (int rg = 0; rg < 4; ++rg) {
                const float o = fmaxf(acc[j][rg] + bbv, 0.f);
                if (p12 == 0) xa[(slab + lg * 4 + rg) * HDIM + col] = o;
                xpan[(lg * 4 + rg) * XPS + col] = f2bf(o);
            }
        }
    }
    __syncthreads();
    const int prob = p12 >> 2, qtr = p12 & 3;
    const ushort* Wt = (prob == 0) ? WqT : (prob == 1) ? WkT : WvT;
    const float*  bb = (prob == 0) ? bq  : (prob == 1) ? bk  : bv;
    qkv_one1(xpan, Wt, bb, prob, slab, qtr * 64 + wv * 16, lr, lg, lk,
             q16, k16, vT16);
}

// ---------------------------------------------------------------------------
// attn_fused: 256 blocks x 512 thr. bid: h = bid>>6; r6 = bid&63:
// slab = (r6>>1)*16, dh = r6&1 (d-half of 32). QK^T+softmax duplicated per
// d-half; PV wave = (db2 = wv&1, kq = wv>>1) over 128-key quarters.
// ---------------------------------------------------------------------------
__global__ __launch_bounds__(512) void attn_fused(
    const ushort* __restrict__ q16, const ushort* __restrict__ k16,
    const ushort* __restrict__ vT16, const float* __restrict__ dist,
    const float* __restrict__ dwraw, const float* __restrict__ inv_cs,
    ushort* __restrict__ ao16)
{
    __shared__ __align__(16) ushort P_lds[16 * PSTR];   // 16.6 KB
    __shared__ __align__(16) float exch[4][16][32];     // 8 KB
    __shared__ float rmax[8][16];
    __shared__ float psums[8][16];

    const int bid = blockIdx.x;
    const int h   = bid >> 6;
    const int r6  = bid & 63;
    const int n0  = (r6 >> 1) * 16;
    const int dh  = r6 & 1;
    const int t  = threadIdx.x;
    const int wv = t >> 6, lane = t & 63;
    const int lr = lane & 15, lg = lane >> 4, lk = lg * 8;
    const int mW = wv * 64;

    const ushort* Qrow = q16 + (n0 + lr) * HDIM + h * DKH + lk;
    const bf16x8 a0 = *(const bf16x8*)&Qrow[0];
    const bf16x8 a1 = *(const bf16x8*)&Qrow[32];

    // ---- S = Q @ K^T (16 x 64 per wave) ----
    f32x4 accs[4];
#pragma unroll
    for (int cg = 0; cg < 4; ++cg) accs[cg] = (f32x4){0.f, 0.f, 0.f, 0.f};
#pragma unroll
    for (int cg = 0; cg < 4; ++cg) {
        const ushort* Brow = k16 + (mW + cg * 16 + lr) * HDIM + h * DKH + lk;
        accs[cg] = __builtin_amdgcn_mfma_f32_16x16x32_bf16(
            a0, *(const bf16x8*)&Brow[0], accs[cg], 0, 0, 0);
        accs[cg] = __builtin_amdgcn_mfma_f32_16x16x32_bf16(
            a1, *(const bf16x8*)&Brow[32], accs[cg], 0, 0, 0);
    }

    // ---- scale + bias ----
    float s[4][4];
#pragma unroll
    for (int cg = 0; cg < 4; ++cg) {
        const int m = mW + cg * 16 + lr;
        const float ic = (h == 0) ? inv_cs[m] : 0.f;
#pragma unroll
        for (int rg = 0; rg < 4; ++rg) {
            const int n = n0 + lg * 4 + rg;
            float b = 0.f;
            if (h == 0)      b = dwraw[n * NTOK + m] * ic;
            else if (h == 1) b = -dist[n * NTOK + m];
            s[cg][rg] = accs[cg][rg] * 0.125f + b;
        }
    }

    // ---- row max ----
    float mx[4];
#pragma unroll
    for (int rg = 0; rg < 4; ++rg) {
        float m = fmaxf(fmaxf(s[0][rg], s[1][rg]), fmaxf(s[2][rg], s[3][rg]));
#pragma unroll
        for (int o = 1; o < 16; o <<= 1) m = fmaxf(m, __shfl_xor(m, o));
        mx[rg] = m;
    }
    if (lr == 0)
#pragma unroll
        for (int rg = 0; rg < 4; ++rg) rmax[wv][lg * 4 + rg] = mx[rg];
    __syncthreads();
    float mxf[4];
#pragma unroll
    for (int rg = 0; rg < 4; ++rg) {
        const int row = lg * 4 + rg;
        float m = rmax[0][row];
#pragma unroll
        for (int w = 1; w < 8; ++w) m = fmaxf(m, rmax[w][row]);
        mxf[rg] = m;
    }

    // ---- exp, partial sums, P -> LDS (bf16) ----
    float ps[4] = {0.f, 0.f, 0.f, 0.f};
#pragma unroll
    for (int cg = 0; cg < 4; ++cg)
#pragma unroll
        for (int rg = 0; rg < 4; ++rg) {
            const float e = __expf(s[cg][rg] - mxf[rg]);
            ps[rg] += e;
            P_lds[(lg * 4 + rg) * PSTR + mW + cg * 16 + lr] = f2bf(e);
        }
#pragma unroll
    for (int rg = 0; rg < 4; ++rg) {
#pragma unroll
        for (int o = 1; o < 16; o <<= 1) ps[rg] += __shfl_xor(ps[rg], o);
    }
    if (lr == 0)
#pragma unroll
        for (int rg = 0; rg < 4; ++rg) psums[wv][lg * 4 + rg] = ps[rg];
    __syncthreads();

    // ---- PV: wave = (db2 = wv&1, kq = wv>>1), 128 keys, 16 d ----
    {
        const int db2 = wv & 1, kq = wv >> 1;
        f32x4 acco = (f32x4){0.f, 0.f, 0.f, 0.f};
        const ushort* Vrow = vT16 + (h * DKH + dh * 32 + db2 * 16 + lr) * NTOK
                           + kq * 128 + lk;
        const ushort* Prow = P_lds + lr * PSTR + kq * 128 + lk;
#pragma unroll
        for (int c = 0; c < 4; ++c) {
            const bf16x8 pa = *(const bf16x8*)&Prow[c * 32];
            const bf16x8 b  = *(const bf16x8*)&Vrow[c * 32];
            acco = __builtin_amdgcn_mfma_f32_16x16x32_bf16(pa, b, acco, 0, 0, 0);
        }
#pragma unroll
        for (int rg = 0; rg < 4; ++rg)
            exch[kq][lg * 4 + rg][db2 * 16 + lr] = acco[rg];
    }
    __syncthreads();

    // ---- combine 4 partials + 1/rowsum + store (threads 0..255, 2 d each) --
    if (t < 256) {
        const int r = t >> 4, dd = (t & 15) * 2;
        float sx = 0.f, sy = 0.f;
#pragma unroll
        for (int kq = 0; kq < 4; ++kq) {
            const float2 e = *(const float2*)&exch[kq][r][dd];
            sx += e.x; sy += e.y;
        }
        float den = 0.f;
#pragma unroll
        for (int w = 0; w < 8; ++w) den += psums[w][r];
        const float inv = 1.0f / den;
        ushort2 o = {f2bf(sx * inv), f2bf(sy * inv)};
        *(ushort2*)&ao16[(n0 + r) * HDIM + h * DKH + dh * 32 + dd] = o;
    }
}

// ---------------------------------------------------------------------------
// oproj+LN phase (proven): normalized values left in acc.
// ---------------------------------------------------------------------------
__device__ __forceinline__ void oprojln_phase(
    const ushort* __restrict__ ao16, const ushort* __restrict__ WoT,
    const float* __restrict__ bo, const float* __restrict__ gamma,
    const float* __restrict__ beta, const float* __restrict__ x,
    int slab, int c0, int wv, int lr, int lg, int lk,
    float red[4][16], f32x4 acc[4])
{
    const ushort* Arow = ao16 + (slab + lr) * HDIM + lk;
#pragma unroll
    for (int j = 0; j < 4; ++j) acc[j] = (f32x4){0.f, 0.f, 0.f, 0.f};
#pragma unroll
    for (int ks = 0; ks < 8; ++ks) {
        const bf16x8 a = *(const bf16x8*)&Arow[ks * 32];
#pragma unroll
        for (int j = 0; j < 4; ++j) {
            const bf16x8 b = *(const bf16x8*)&WoT[(c0 + j * 16 + lr) * HDIM + ks * 32 + lk];
            acc[j] = __builtin_amdgcn_mfma_f32_16x16x32_bf16(a, b, acc[j], 0, 0, 0);
        }
    }
#pragma unroll
    for (int j = 0; j < 4; ++j) {
        const int col = c0 + j * 16 + lr;
        const float bc = bo[col];
#pragma unroll
        for (int rg = 0; rg < 4; ++rg)
            acc[j][rg] += bc + x[(slab + lg * 4 + rg) * HDIM + col];
    }

    float sm[4];
#pragma unroll
    for (int rg = 0; rg < 4; ++rg) {
        float s = 0.f;
#pragma unroll
        for (int j = 0; j < 4; ++j) s += acc[j][rg];
#pragma unroll
        for (int o = 1; o < 16; o <<= 1) s += __shfl_xor(s, o);
        sm[rg] = s;
    }
    if (lr == 0)
#pragma unroll
        for (int rg = 0; rg < 4; ++rg) red[wv][lg * 4 + rg] = sm[rg];
    __syncthreads();
    float mean[4];
#pragma unroll
    for (int rg = 0; rg < 4; ++rg) {
        const int row = lg * 4 + rg;
        mean[rg] = (red[0][row] + red[1][row] + red[2][row] + red[3][row]) * (1.f / 256.f);
    }
    __syncthreads();

#pragma unroll
    for (int rg = 0; rg < 4; ++rg) {
        float s2 = 0.f;
#pragma unroll
        for (int j = 0; j < 4; ++j) {
            const float c = acc[j][rg] - mean[rg];
            s2 += c * c;
        }
#pragma unroll
        for (int o = 1; o < 16; o <<= 1) s2 += __shfl_xor(s2, o);
        sm[rg] = s2;
    }
    if (lr == 0)
#pragma unroll
        for (int rg = 0; rg < 4; ++rg) red[wv][lg * 4 + rg] = sm[rg];
    __syncthreads();
    float rstd[4];
#pragma unroll
    for (int rg = 0; rg < 4; ++rg) {
        const int row = lg * 4 + rg;
        const float var = (red[0][row] + red[1][row] + red[2][row] + red[3][row]) * (1.f / 256.f);
        rstd[rg] = rsqrtf(var + 1e-5f);
    }
#pragma unroll
    for (int j = 0; j < 4; ++j) {
        const int col = c0 + j * 16 + lr;
        const float gg = gamma[col], bv = beta[col];
#pragma unroll
        for (int rg = 0; rg < 4; ++rg)
            acc[j][rg] = (acc[j][rg] - mean[rg]) * rstd[rg] * gg + bv;
    }
}

// ---------------------------------------------------------------------------
// oprojqkv: 384 blocks. p12 = bid>>5: prob = p12>>2, qtr = p12&3.
// ---------------------------------------------------------------------------
__global__ __launch_bounds__(256) void oprojqkv(
    const ushort* __restrict__ ao16, const ushort* __restrict__ WoT,
    const float* __restrict__ bo, const float* __restrict__ gamma,
    const float* __restrict__ beta,
    const ushort* __restrict__ WqT, const float* __restrict__ bq,
    const ushort* __restrict__ WkT, const float* __restrict__ bk,
    const ushort* __restrict__ WvT, const float* __restrict__ bv,
    const float* __restrict__ xa, float* __restrict__ xb,
    ushort* __restrict__ q16, ushort* __restrict__ k16,
    ushort* __restrict__ vT16)
{
    __shared__ __align__(16) ushort xpan[16 * XPS];
    __shared__ float red[4][16];
    const int bid  = blockIdx.x;
    const int p12  = bid >> 5;
    const int slab = (bid & 31) * 16;
    const int t = threadIdx.x;
    const int wv = t >> 6, lane = t & 63;
    const int lr = lane & 15, lg = lane >> 4, lk = lg * 8;
    const int c0 = wv * 64;

    f32x4 acc[4];
    oprojln_phase(ao16, WoT, bo, gamma, beta, xa, slab, c0, wv, lr, lg, lk, red, acc);
#pragma unroll
    for (int j = 0; j < 4; ++j) {
        const int col = c0 + j * 16 + lr;
#pragma unroll
        for (int rg = 0; rg < 4; ++rg) {
            if (p12 == 0) xb[(slab + lg * 4 + rg) * HDIM + col] = acc[j][rg];
            xpan[(lg * 4 + rg) * XPS + col] = f2bf(acc[j][rg]);
        }
    }
    __syncthreads();
    const int prob = p12 >> 2, qtr = p12 & 3;
    const ushort* Wt = (prob == 0) ? WqT : (prob == 1) ? WkT : WvT;
    const float*  bb = (prob == 0) ? bq  : (prob == 1) ? bk  : bv;
    qkv_one1(xpan, Wt, bb, prob, slab, qtr * 64 + wv * 16, lr, lg, lk,
             q16, k16, vT16);
}

// ---------------------------------------------------------------------------
// oprojmlpU: 256 blocks. p8 = bid>>5: p = p8>>2, qtr = p8&3.
// Phase 3: one col-group at qtr*64 + wv*16. U1/U2 bf16 out.
// ---------------------------------------------------------------------------
__global__ __launch_bounds__(256) void oprojmlpU(
    const ushort* __restrict__ ao16, const ushort* __restrict__ WoT,
    const float* __restrict__ bo, const float* __restrict__ gamma,
    const float* __restrict__ beta,
    const ushort* __restrict__ m1WT, const float* __restrict__ m1b,
    const ushort* __restrict__ m2WT, const float* __restrict__ m2b,
    const ushort* __restrict__ cW1aT, const float* __restrict__ cb1,
    const ushort* __restrict__ cW1bT,
    const float* __restrict__ xb, ushort* __restrict__ U1b,
    ushort* __restrict__ U2b)
{
    __shared__ __align__(16) ushort xpan[16 * XPS];
    __shared__ __align__(16) ushort opan[16 * XPS];
    __shared__ float red[4][16];
    const int bid  = blockIdx.x;
    const int p8   = bid >> 5;
    const int p    = p8 >> 2, qtr = p8 & 3;
    const int slab = (bid & 31) * 16;
    const int t = threadIdx.x;
    const int wv = t >> 6, lane = t & 63;
    const int lr = lane & 15, lg = lane >> 4, lk = lg * 8;
    const int c0 = wv * 64;

    f32x4 acc[4];
    oprojln_phase(ao16, WoT, bo, gamma, beta, xb, slab, c0, wv, lr, lg, lk, red, acc);
#pragma unroll
    for (int j = 0; j < 4; ++j) {
        const int col = c0 + j * 16 + lr;
#pragma unroll
        for (int rg = 0; rg < 4; ++rg)
            xpan[(lg * 4 + rg) * XPS + col] = f2bf(acc[j][rg]);
    }
    __syncthreads();

    {   // phase 2: full o_p panel
        const ushort* Wt = p ? m2WT : m1WT;
        const float*  bb = p ? m2b  : m1b;
        const ushort* Ap = xpan + lr * XPS + lk;
        f32x4 a2[4];
#pragma unroll
        for (int j = 0; j < 4; ++j) a2[j] = (f32x4){0.f, 0.f, 0.f, 0.f};
#pragma unroll
        for (int ks = 0; ks < 8; ++ks) {
            const bf16x8 a = *(const bf16x8*)&Ap[ks * 32];
#pragma unroll
            for (int j = 0; j < 4; ++j) {
                const bf16x8 b = *(const bf16x8*)&Wt[(c0 + j * 16 + lr) * HDIM + ks * 32 + lk];
                a2[j] = __builtin_amdgcn_mfma_f32_16x16x32_bf16(a, b, a2[j], 0, 0, 0);
            }
        }
#pragma unroll
        for (int j = 0; j < 4; ++j) {
            const int col = c0 + j * 16 + lr;
            const float bbv = bb[col];
#pragma unroll
            for (int rg = 0; rg < 4; ++rg)
                opan[(lg * 4 + rg) * XPS + col] = f2bf(fmaxf(a2[j][rg] + bbv, 0.f));
        }
    }
    __syncthreads();

    {   // phase 3: U_p, one col-group, bf16 output
        const ushort* Wt = p ? cW1bT : cW1aT;
        ushort* U        = p ? U2b : U1b;
        const int cb     = qtr * 64 + wv * 16;
        const ushort* Ao = opan + lr * XPS + lk;
        f32x4 a2 = (f32x4){0.f, 0.f, 0.f, 0.f};
#pragma unroll
        for (int ks = 0; ks < 8; ++ks) {
            const bf16x8 a = *(const bf16x8*)&Ao[ks * 32];
            const bf16x8 b = *(const bf16x8*)&Wt[(cb + lr) * HDIM + ks * 32 + lk];
            a2 = __builtin_amdgcn_mfma_f32_16x16x32_bf16(a, b, a2, 0, 0, 0);
        }
        const int col = cb + lr;
        const float bbv = (p == 0) ? cb1[col] : 0.f;
#pragma unroll
        for (int rg = 0; rg < 4; ++rg)
            U[(slab + lg * 4 + rg) * HDIM + col] = f2bf(a2[rg] + bbv);
    }
}

// ---------------------------------------------------------------------------
// pair_cls: 32x32 tile, 2x2/thread, bf16 LDS panels, f32 w2. (proven)
// ---------------------------------------------------------------------------
__global__ __launch_bounds__(256) void pair_cls(const ushort* __restrict__ U1b,
                                                const ushort* __restrict__ U2b,
                                                const float* __restrict__ W2,
                                                const float* __restrict__ b2,
                                                float* __restrict__ out)
{
    __shared__ __align__(16) ushort u1s[32][264];
    __shared__ __align__(16) ushort u2s[32][264];
    __shared__ __align__(16) float w2s[256];
    const int t  = threadIdx.x;
    const int n0 = blockIdx.y * 32, m0 = blockIdx.x * 32;

#pragma unroll
    for (int u = 0; u < 4; ++u) {
        const int i = t + u * 256;
        const int r = i >> 5, c8 = i & 31;
        *(uint4*)&u1s[r][c8 * 8] = *(const uint4*)&U1b[(n0 + r) * HDIM + c8 * 8];
        *(uint4*)&u2s[r][c8 * 8] = *(const uint4*)&U2b[(m0 + r) * HDIM + c8 * 8];
    }
    if (t < 64) *(float4*)&w2s[t * 4] = *(const float4*)&W2[t * 4];
    __syncthreads();

    const int tx = t & 15, ty = t >> 4;
    const ushort* r0 = &u1s[ty * 2][0];
    const ushort* r1 = &u1s[ty * 2 + 1][0];
    const ushort* c0 = &u2s[tx * 2][0];
    const ushort* c1 = &u2s[tx * 2 + 1][0];
    float acc[2][2] = {};

#define RT(A, B) fmaxf((A) + (B), 0.f)
    for (int h8 = 0; h8 < 32; ++h8) {
        const uint4 A0 = *(const uint4*)&r0[h8 * 8];
        const uint4 A1 = *(const uint4*)&r1[h8 * 8];
        const uint4 B0 = *(const uint4*)&c0[h8 * 8];
        const uint4 B1 = *(const uint4*)&c1[h8 * 8];
        const float4 w0 = *(const float4*)&w2s[h8 * 8];
        const float4 w1 = *(const float4*)&w2s[h8 * 8 + 4];
        const float warr[8] = {w0.x, w0.y, w0.z, w0.w, w1.x, w1.y, w1.z, w1.w};
#pragma unroll
        for (int q = 0; q < 4; ++q) {
            const unsigned a0u = ((const unsigned*)&A0)[q];
            const unsigned a1u = ((const unsigned*)&A1)[q];
            const unsigned b0u = ((const unsigned*)&B0)[q];
            const unsigned b1u = ((const unsigned*)&B1)[q];
            const float a0l = bf_lo(a0u), a0h = bf_hi(a0u);
            const float a1l = bf_lo(a1u), a1h = bf_hi(a1u);
            const float b0l = bf_lo(b0u), b0h = bf_hi(b0u);
            const float b1l = bf_lo(b1u), b1h = bf_hi(b1u);
            const float wl = warr[q * 2], wh = warr[q * 2 + 1];
            acc[0][0] += RT(a0l, b0l) * wl + RT(a0h, b0h) * wh;
            acc[0][1] += RT(a0l, b1l) * wl + RT(a0h, b1h) * wh;
            acc[1][0] += RT(a1l, b0l) * wl + RT(a1h, b1h) * 0.f + RT(a1h, b0h) * wh;
            acc[1][1] += RT(a1l, b1l) * wl + RT(a1h, b1h) * wh;
        }
    }
#undef RT

    const float bbv = b2[0];
#pragma unroll
    for (int ii = 0; ii < 2; ++ii)
#pragma unroll
        for (int jj = 0; jj < 2; ++jj) {
            const float val = acc[ii][jj] + bbv;
            const int n = n0 + ty * 2 + ii;
            const int m = m0 + tx * 2 + jj;
#pragma unroll
            for (int tl = 0; tl < TLEN; ++tl)
                out[tl * NTOK * NTOK + n * NTOK + m] = val;
        }
}

// ---------------------------------------------------------------------------
extern "C" void kernel_launch(void* const* d_in, const int* in_sizes, int n_in,
                              void* d_out, int out_size, void* d_ws, size_t ws_size,
                              hipStream_t stream)
{
    const float* hs   = (const float*)d_in[0];
    const float* qf   = hs + 5 * NTOK * HDIM;
    const float* alp  = (const float*)d_in[1];
    const float* pl   = alp + 5 * NTOK * 33;
    const float* fc_W = (const float*)d_in[2];
    const float* fc_b = (const float*)d_in[3];
    const float* Wq   = (const float*)d_in[4];
    const float* bq   = (const float*)d_in[5];
    const float* Wk   = (const float*)d_in[6];
    const float* bk   = (const float*)d_in[7];
    const float* Wv   = (const float*)d_in[8];
    const float* bv   = (const float*)d_in[9];
    const float* Wo   = (const float*)d_in[10];
    const float* bo   = (const float*)d_in[11];
    const float* lng  = (const float*)d_in[12];
    const float* lnb  = (const float*)d_in[13];
    const float* m1W  = (const float*)d_in[14];
    const float* m1b  = (const float*)d_in[15];
    const float* m2W  = (const float*)d_in[16];
    const float* m2b  = (const float*)d_in[17];
    const float* cW1  = (const float*)d_in[18];
    const float* cb1  = (const float*)d_in[19];
    const float* cW2  = (const float*)d_in[20];
    const float* cb2  = (const float*)d_in[21];
    float* out = (float*)d_out;

    const int NN  = NTOK * NTOK;
    const int NH_ = NTOK * HDIM;
    float* ws     = (float*)d_ws;
    float* dist   = ws;                       // NN
    float* dwraw  = ws + NN;                  // NN
    float* inv_cs = ws + 2 * NN;              // 512
    float* xa     = ws + 2 * NN + 512;        // NH
    float* xb     = xa + NH_;                 // NH
    ushort* u16   = (ushort*)(xb + NH_);
    ushort* wpk   = u16;                      // 13 * WSZ
    ushort* q16   = wpk + 13 * WSZ;           // NH
    ushort* k16   = q16 + NH_;                // NH
    ushort* vT16  = k16 + NH_;                // NH ([d][m])
    ushort* ao16  = vT16 + NH_;               // NH
    ushort* U1b   = ao16 + NH_;               // NH
    ushort* U2b   = U1b + NH_;                // NH

    PKArg pk;
    pk.w[0]  = fc_W;
    pk.w[1]  = Wq;  pk.w[2]  = Wq + WSZ;
    pk.w[3]  = Wk;  pk.w[4]  = Wk + WSZ;
    pk.w[5]  = Wv;  pk.w[6]  = Wv + WSZ;
    pk.w[7]  = Wo;  pk.w[8]  = Wo + WSZ;
    pk.w[9]  = m1W; pk.w[10] = m2W;
    pk.w[11] = cW1; pk.w[12] = cW1 + WSZ;
    pk.pl = pl;
    pk.wpk = wpk;
    pk.dist = dist; pk.dwraw = dwraw; pk.inv_cs = inv_cs;
    pack_kernel<<<216, 256, 0, stream>>>(pk);

    fcqkv<<<384, 256, 0, stream>>>(
        qf, wpk + 0 * WSZ, fc_b,
        wpk + 1 * WSZ, bq, wpk + 3 * WSZ, bk, wpk + 5 * WSZ, bv,
        xa, q16, k16, vT16);

    attn_fused<<<256, 512, 0, stream>>>(q16, k16, vT16, dist, dwraw, inv_cs, ao16);

    oprojqkv<<<384, 256, 0, stream>>>(
        ao16, wpk + 7 * WSZ, bo, lng, lnb,
        wpk + 2 * WSZ, bq + HDIM, wpk + 4 * WSZ, bk + HDIM,
        wpk + 6 * WSZ, bv + HDIM,
        xa, xb, q16, k16, vT16);

    attn_fused<<<256, 512, 0, stream>>>(q16, k16, vT16, dist, dwraw, inv_cs, ao16);

    oprojmlpU<<<256, 256, 0, stream>>>(
        ao16, wpk + 8 * WSZ, bo + HDIM, lng + HDIM, lnb + HDIM,
        wpk + 9 * WSZ, m1b, wpk + 10 * WSZ, m2b,
        wpk + 11 * WSZ, cb1, wpk + 12 * WSZ,
        xb, U1b, U2b);

    pair_cls<<<dim3(16, 16), 256, 0, stream>>>(U1b, U2b, cW2, cb2, out);
}

// Round 16
// 95.284 us; speedup vs baseline: 1.0885x; 1.0885x over previous
//
#include <hip/hip_runtime.h>
#include <math.h>

// ---------------------------------------------------------------------------
// SpatialProximityHead on MI355X — round 15: r13 (best, 95.7us) + attn V-frag
// prefetch (V loads hoisted above softmax barriers). 7 dispatches.
// pack(216) -> fcqkv(192) -> attn(128x512) -> oprojqkv(192) -> attn
//           -> oprojmlpU(128) -> pair(256)
// ---------------------------------------------------------------------------

#define NTOK 512
#define HDIM 256
#define DKH  64
#define NHEAD 4
#define TLEN 6
#define WSZ  65536
#define PSTR 520   // attn P_lds ushort stride
#define XPS  264   // LDS panel ushort stride

typedef __attribute__((ext_vector_type(8))) short bf16x8;
typedef __attribute__((ext_vector_type(4))) float f32x4;

__device__ __forceinline__ ushort f2bf(float f)
{
    unsigned u = __builtin_bit_cast(unsigned, f);
    u += 0x7FFFu + ((u >> 16) & 1u);     // RNE
    return (ushort)(u >> 16);
}
__device__ __forceinline__ float bf_lo(unsigned u)
{
    return __builtin_bit_cast(float, u << 16);
}
__device__ __forceinline__ float bf_hi(unsigned u)
{
    return __builtin_bit_cast(float, u & 0xFFFF0000u);
}

struct PKArg {
    const float* w[13];
    const float* pl;
    ushort* wpk;
    float *dist, *dwraw, *inv_cs;
};

// ---------------------------------------------------------------------------
// pack: 0-207 weight 64x64 transpose tiles ([col][k] bf16); 208-215 dist prep.
// ---------------------------------------------------------------------------
__global__ __launch_bounds__(256) void pack_kernel(PKArg p)
{
    __shared__ __align__(16) ushort smu[64 * 72];
    const int bid = blockIdx.x;
    const int t   = threadIdx.x;

    if (bid < 208) {
        const int mat  = bid >> 4;
        const int tile = bid & 15;
        const int k0   = (tile >> 2) * 64;
        const int c0   = (tile & 3) * 64;
        const float* W = p.w[mat];
#pragma unroll
        for (int j = 0; j < 4; ++j) {
            const int i  = t + j * 256;
            const int r  = i >> 4, c4 = i & 15;
            const float4 v4 = *(const float4*)&W[(k0 + r) * HDIM + c0 + c4 * 4];
            smu[(c4 * 4 + 0) * 72 + r] = f2bf(v4.x);
            smu[(c4 * 4 + 1) * 72 + r] = f2bf(v4.y);
            smu[(c4 * 4 + 2) * 72 + r] = f2bf(v4.z);
            smu[(c4 * 4 + 3) * 72 + r] = f2bf(v4.w);
        }
        __syncthreads();
#pragma unroll
        for (int j = 0; j < 2; ++j) {
            const int i  = t + j * 256;
            const int cr = i >> 3, kk = i & 7;
            const uint4 v = *(const uint4*)&smu[cr * 72 + kk * 8];
            *(uint4*)&p.wpk[mat * WSZ + (c0 + cr) * HDIM + k0 + kk * 8] = v;
        }
    } else {
        float* smf = (float*)smu;
        float* qe  = smf;            // [512][3]
        float* red = smf + 1536;     // [4][64]
        const int item = bid - 208;
        for (int i = t; i < 512; i += 256) {
            qe[i * 3 + 0] = p.pl[i * 33 + 30];
            qe[i * 3 + 1] = p.pl[i * 33 + 31];
            qe[i * 3 + 2] = p.pl[i * 33 + 32];
        }
        __syncthreads();
        const int m   = item * 64 + (t & 63);
        const int nch = t >> 6;
        const float kx = p.pl[m * 33 + 0], ky = p.pl[m * 33 + 1], kz = p.pl[m * 33 + 2];
        float cs = 0.f;
        for (int n = nch * 128; n < nch * 128 + 128; ++n) {
            const float dx = kx - qe[n * 3 + 0];
            const float dy = ky - qe[n * 3 + 1];
            const float dz = kz - qe[n * 3 + 2];
            const float dd = sqrtf(dx * dx + dy * dy + dz * dz);
            const float w  = 1.0f / (dd + 0.01f);
            p.dist[n * NTOK + m]  = dd;
            p.dwraw[n * NTOK + m] = w;
            cs += w;
        }
        red[nch * 64 + (t & 63)] = cs;
        __syncthreads();
        if (t < 64)
            p.inv_cs[item * 64 + t] =
                1.0f / (red[t] + red[64 + t] + red[128 + t] + red[192 + t]);
    }
}

// ---------------------------------------------------------------------------
// qkv_one2: one qkv problem, 2 col-groups starting at c0. prob: 0->q16,
// 1->k16 (row-major), 2->vT16 (transposed).
// ---------------------------------------------------------------------------
__device__ __forceinline__ void qkv_one2(
    const ushort* __restrict__ xpan, const ushort* __restrict__ Wt,
    const float* __restrict__ bb, int prob,
    int slab, int c0, int lr, int lg, int lk,
    ushort* __restrict__ q16, ushort* __restrict__ k16,
    ushort* __restrict__ vT16)
{
    const ushort* Ap = xpan + lr * XPS + lk;
    f32x4 acc[2];
    acc[0] = (f32x4){0.f, 0.f, 0.f, 0.f};
    acc[1] = (f32x4){0.f, 0.f, 0.f, 0.f};
#pragma unroll
    for (int ks = 0; ks < 8; ++ks) {
        const bf16x8 a = *(const bf16x8*)&Ap[ks * 32];
#pragma unroll
        for (int j = 0; j < 2; ++j) {
            const bf16x8 b = *(const bf16x8*)&Wt[(c0 + j * 16 + lr) * HDIM + ks * 32 + lk];
            acc[j] = __builtin_amdgcn_mfma_f32_16x16x32_bf16(a, b, acc[j], 0, 0, 0);
        }
    }
#pragma unroll
    for (int j = 0; j < 2; ++j) {
        const int col = c0 + j * 16 + lr;
        const float bv2 = bb[col];
        if (prob < 2) {
            ushort* dst = (prob == 0) ? q16 : k16;
#pragma unroll
            for (int rg = 0; rg < 4; ++rg)
                dst[(slab + lg * 4 + rg) * HDIM + col] = f2bf(acc[j][rg] + bv2);
        } else {
            ushort4 s = {f2bf(acc[j][0] + bv2), f2bf(acc[j][1] + bv2),
                         f2bf(acc[j][2] + bv2), f2bf(acc[j][3] + bv2)};
            *(ushort4*)&vT16[col * NTOK + slab + lg * 4] = s;
        }
    }
}

// ---------------------------------------------------------------------------
// fcqkv: 192 blocks. p6 = bid>>5 (0..5): prob = p6>>1, ch = p6&1.
// ---------------------------------------------------------------------------
__global__ __launch_bounds__(256) void fcqkv(
    const float* __restrict__ qf, const ushort* __restrict__ fcWt,
    const float* __restrict__ fcb,
    const ushort* __restrict__ WqT, const float* __restrict__ bq,
    const ushort* __restrict__ WkT, const float* __restrict__ bk,
    const ushort* __restrict__ WvT, const float* __restrict__ bv,
    float* __restrict__ xa, ushort* __restrict__ q16,
    ushort* __restrict__ k16, ushort* __restrict__ vT16)
{
    __shared__ __align__(16) ushort xpan[16 * XPS];
    const int bid  = blockIdx.x;
    const int p6   = bid >> 5;
    const int slab = (bid & 31) * 16;
    const int t = threadIdx.x;
    const int wv = t >> 6, lane = t & 63;
    const int lr = lane & 15, lg = lane >> 4, lk = lg * 8;
    const int c0 = wv * 64;

    {   // phase 1: fc (replicated)
        f32x4 acc[4];
#pragma unroll
        for (int j = 0; j < 4; ++j) acc[j] = (f32x4){0.f, 0.f, 0.f, 0.f};
        const float* Aq = qf + (slab + lr) * HDIM + lk;
#pragma unroll
        for (int ks = 0; ks < 8; ++ks) {
            const float4 a0 = *(const float4*)&Aq[ks * 32];
            const float4 a1 = *(const float4*)&Aq[ks * 32 + 4];
            bf16x8 a;
            a[0] = (short)f2bf(a0.x); a[1] = (short)f2bf(a0.y);
            a[2] = (short)f2bf(a0.z); a[3] = (short)f2bf(a0.w);
            a[4] = (short)f2bf(a1.x); a[5] = (short)f2bf(a1.y);
            a[6] = (short)f2bf(a1.z); a[7] = (short)f2bf(a1.w);
#pragma unroll
            for (int j = 0; j < 4; ++j) {
                const bf16x8 b = *(const bf16x8*)&fcWt[(c0 + j * 16 + lr) * HDIM + ks * 32 + lk];
                acc[j] = __builtin_amdgcn_mfma_f32_16x16x32_bf16(a, b, acc[j], 0, 0, 0);
            }
        }
#pragma unroll
        for (int j = 0; j < 4; ++j) {
            const int col = c0 + j * 16 + lr;
            const float bbv = fcb[col];
#pragma unroll
            for (int rg = 0; rg < 4; ++rg) {
                const float o = fmaxf(acc[j][rg] + bbv, 0.f);
                if (p6 == 0) xa[(slab + lg * 4 + rg) * HDIM + col] = o;
                xpan[(lg * 4 + rg) * XPS + col] = f2bf(o);
            }
        }
    }
    __syncthreads();
    const int prob = p6 >> 1, ch = p6 & 1;
    const ushort* Wt = (prob == 0) ? WqT : (prob == 1) ? WkT : WvT;
    const float*  bb = (prob == 0) ? bq  : (prob == 1) ? bk  : bv;
    qkv_one2(xpan, Wt, bb, prob, slab, ch * 128 + wv * 32, lr, lg, lk,
             q16, k16, vT16);
}

// ---------------------------------------------------------------------------
// attn_fused: 128 blocks x 512 thr. QK^T wave = key-slice of 64;
// PV wave = (db = wv&3, kh = wv>>2), V fragments PREFETCHED before softmax.
// ---------------------------------------------------------------------------
__global__ __launch_bounds__(512) void attn_fused(
    const ushort* __restrict__ q16, const ushort* __restrict__ k16,
    const ushort* __restrict__ vT16, const float* __restrict__ dist,
    const float* __restrict__ dwraw, const float* __restrict__ inv_cs,
    ushort* __restrict__ ao16)
{
    __shared__ __align__(16) ushort P_lds[16 * PSTR];   // 16.6 KB
    __shared__ __align__(16) float exch[2][16][64];     // 8 KB
    __shared__ float rmax[8][16];
    __shared__ float psums[8][16];

    const int bid = blockIdx.x;
    const int h  = bid >> 5;
    const int n0 = (bid & 31) * 16;
    const int t  = threadIdx.x;
    const int wv = t >> 6, lane = t & 63;
    const int lr = lane & 15, lg = lane >> 4, lk = lg * 8;
    const int mW = wv * 64;

    const ushort* Qrow = q16 + (n0 + lr) * HDIM + h * DKH + lk;
    const bf16x8 a0 = *(const bf16x8*)&Qrow[0];
    const bf16x8 a1 = *(const bf16x8*)&Qrow[32];

    // ---- S = Q @ K^T (16 x 64 per wave) ----
    f32x4 accs[4];
#pragma unroll
    for (int cg = 0; cg < 4; ++cg) accs[cg] = (f32x4){0.f, 0.f, 0.f, 0.f};
#pragma unroll
    for (int cg = 0; cg < 4; ++cg) {
        const ushort* Brow = k16 + (mW + cg * 16 + lr) * HDIM + h * DKH + lk;
        accs[cg] = __builtin_amdgcn_mfma_f32_16x16x32_bf16(
            a0, *(const bf16x8*)&Brow[0], accs[cg], 0, 0, 0);
        accs[cg] = __builtin_amdgcn_mfma_f32_16x16x32_bf16(
            a1, *(const bf16x8*)&Brow[32], accs[cg], 0, 0, 0);
    }

    // ---- PREFETCH V fragments for PV (independent of softmax) ----
    const int db = wv & 3, kh = wv >> 2;
    const ushort* Vrow = vT16 + (h * DKH + db * 16 + lr) * NTOK + kh * 256 + lk;
    bf16x8 vfrag[8];
#pragma unroll
    for (int c = 0; c < 8; ++c)
        vfrag[c] = *(const bf16x8*)&Vrow[c * 32];

    // ---- scale + bias ----
    float s[4][4];
#pragma unroll
    for (int cg = 0; cg < 4; ++cg) {
        const int m = mW + cg * 16 + lr;
        const float ic = (h == 0) ? inv_cs[m] : 0.f;
#pragma unroll
        for (int rg = 0; rg < 4; ++rg) {
            const int n = n0 + lg * 4 + rg;
            float b = 0.f;
            if (h == 0)      b = dwraw[n * NTOK + m] * ic;
            else if (h == 1) b = -dist[n * NTOK + m];
            s[cg][rg] = accs[cg][rg] * 0.125f + b;
        }
    }

    // ---- row max ----
    float mx[4];
#pragma unroll
    for (int rg = 0; rg < 4; ++rg) {
        float m = fmaxf(fmaxf(s[0][rg], s[1][rg]), fmaxf(s[2][rg], s[3][rg]));
#pragma unroll
        for (int o = 1; o < 16; o <<= 1) m = fmaxf(m, __shfl_xor(m, o));
        mx[rg] = m;
    }
    if (lr == 0)
#pragma unroll
        for (int rg = 0; rg < 4; ++rg) rmax[wv][lg * 4 + rg] = mx[rg];
    __syncthreads();
    float mxf[4];
#pragma unroll
    for (int rg = 0; rg < 4; ++rg) {
        const int row = lg * 4 + rg;
        float m = rmax[0][row];
#pragma unroll
        for (int w = 1; w < 8; ++w) m = fmaxf(m, rmax[w][row]);
        mxf[rg] = m;
    }

    // ---- exp, partial sums, P -> LDS (bf16) ----
    float ps[4] = {0.f, 0.f, 0.f, 0.f};
#pragma unroll
    for (int cg = 0; cg < 4; ++cg)
#pragma unroll
        for (int rg = 0; rg < 4; ++rg) {
            const float e = __expf(s[cg][rg] - mxf[rg]);
            ps[rg] += e;
            P_lds[(lg * 4 + rg) * PSTR + mW + cg * 16 + lr] = f2bf(e);
        }
#pragma unroll
    for (int rg = 0; rg < 4; ++rg) {
#pragma unroll
        for (int o = 1; o < 16; o <<= 1) ps[rg] += __shfl_xor(ps[rg], o);
    }
    if (lr == 0)
#pragma unroll
        for (int rg = 0; rg < 4; ++rg) psums[wv][lg * 4 + rg] = ps[rg];
    __syncthreads();

    // ---- PV: wave = (db, kh), 256 keys each, V already in registers ----
    {
        f32x4 acco = (f32x4){0.f, 0.f, 0.f, 0.f};
        const ushort* Prow = P_lds + lr * PSTR + kh * 256 + lk;
#pragma unroll
        for (int c = 0; c < 8; ++c) {
            const bf16x8 pa = *(const bf16x8*)&Prow[c * 32];
            acco = __builtin_amdgcn_mfma_f32_16x16x32_bf16(pa, vfrag[c], acco, 0, 0, 0);
        }
#pragma unroll
        for (int rg = 0; rg < 4; ++rg)
            exch[kh][lg * 4 + rg][db * 16 + lr] = acco[rg];
    }
    __syncthreads();

    // ---- combine 2 partials + 1/rowsum + store (threads 0..255) ----
    if (t < 256) {
        const int r = t >> 4, d4 = t & 15;
        f32x4 sum = *(const f32x4*)&exch[0][r][d4 * 4];
        sum += *(const f32x4*)&exch[1][r][d4 * 4];
        float den = 0.f;
#pragma unroll
        for (int w = 0; w < 8; ++w) den += psums[w][r];
        const float inv = 1.0f / den;
        ushort4 o = {f2bf(sum.x * inv), f2bf(sum.y * inv),
                     f2bf(sum.z * inv), f2bf(sum.w * inv)};
        *(ushort4*)&ao16[(n0 + r) * HDIM + h * DKH + d4 * 4] = o;
    }
}

// ---------------------------------------------------------------------------
// oproj+LN phase (proven): normalized values left in acc.
// ---------------------------------------------------------------------------
__device__ __forceinline__ void oprojln_phase(
    const ushort* __restrict__ ao16, const ushort* __restrict__ WoT,
    const float* __restrict__ bo, const float* __restrict__ gamma,
    const float* __restrict__ beta, const float* __restrict__ x,
    int slab, int c0, int wv, int lr, int lg, int lk,
    float red[4][16], f32x4 acc[4])
{
    const ushort* Arow = ao16 + (slab + lr) * HDIM + lk;
#pragma unroll
    for (int j = 0; j < 4; ++j) acc[j] = (f32x4){0.f, 0.f, 0.f, 0.f};
#pragma unroll
    for (int ks = 0; ks < 8; ++ks) {
        const bf16x8 a = *(const bf16x8*)&Arow[ks * 32];
#pragma unroll
        for (int j = 0; j < 4; ++j) {
            const bf16x8 b = *(const bf16x8*)&WoT[(c0 + j * 16 + lr) * HDIM + ks * 32 + lk];
            acc[j] = __builtin_amdgcn_mfma_f32_16x16x32_bf16(a, b, acc[j], 0, 0, 0);
        }
    }
#pragma unroll
    for (int j = 0; j < 4; ++j) {
        const int col = c0 + j * 16 + lr;
        const float bc = bo[col];
#pragma unroll
        for (int rg = 0; rg < 4; ++rg)
            acc[j][rg] += bc + x[(slab + lg * 4 + rg) * HDIM + col];
    }

    float sm[4];
#pragma unroll
    for (int rg = 0; rg < 4; ++rg) {
        float s = 0.f;
#pragma unroll
        for (int j = 0; j < 4; ++j) s += acc[j][rg];
#pragma unroll
        for (int o = 1; o < 16; o <<= 1) s += __shfl_xor(s, o);
        sm[rg] = s;
    }
    if (lr == 0)
#pragma unroll
        for (int rg = 0; rg < 4; ++rg) red[wv][lg * 4 + rg] = sm[rg];
    __syncthreads();
    float mean[4];
#pragma unroll
    for (int rg = 0; rg < 4; ++rg) {
        const int row = lg * 4 + rg;
        mean[rg] = (red[0][row] + red[1][row] + red[2][row] + red[3][row]) * (1.f / 256.f);
    }
    __syncthreads();

#pragma unroll
    for (int rg = 0; rg < 4; ++rg) {
        float s2 = 0.f;
#pragma unroll
        for (int j = 0; j < 4; ++j) {
            const float c = acc[j][rg] - mean[rg];
            s2 += c * c;
        }
#pragma unroll
        for (int o = 1; o < 16; o <<= 1) s2 += __shfl_xor(s2, o);
        sm[rg] = s2;
    }
    if (lr == 0)
#pragma unroll
        for (int rg = 0; rg < 4; ++rg) red[wv][lg * 4 + rg] = sm[rg];
    __syncthreads();
    float rstd[4];
#pragma unroll
    for (int rg = 0; rg < 4; ++rg) {
        const int row = lg * 4 + rg;
        const float var = (red[0][row] + red[1][row] + red[2][row] + red[3][row]) * (1.f / 256.f);
        rstd[rg] = rsqrtf(var + 1e-5f);
    }
#pragma unroll
    for (int j = 0; j < 4; ++j) {
        const int col = c0 + j * 16 + lr;
        const float gg = gamma[col], bv = beta[col];
#pragma unroll
        for (int rg = 0; rg < 4; ++rg)
            acc[j][rg] = (acc[j][rg] - mean[rg]) * rstd[rg] * gg + bv;
    }
}

// ---------------------------------------------------------------------------
// oprojqkv: 192 blocks. p6 = bid>>5: prob = p6>>1, ch = p6&1.
// ---------------------------------------------------------------------------
__global__ __launch_bounds__(256) void oprojqkv(
    const ushort* __restrict__ ao16, const ushort* __restrict__ WoT,
    const float* __restrict__ bo, const float* __restrict__ gamma,
    const float* __restrict__ beta,
    const ushort* __restrict__ WqT, const float* __restrict__ bq,
    const ushort* __restrict__ WkT, const float* __restrict__ bk,
    const ushort* __restrict__ WvT, const float* __restrict__ bv,
    const float* __restrict__ xa, float* __restrict__ xb,
    ushort* __restrict__ q16, ushort* __restrict__ k16,
    ushort* __restrict__ vT16)
{
    __shared__ __align__(16) ushort xpan[16 * XPS];
    __shared__ float red[4][16];
    const int bid  = blockIdx.x;
    const int p6   = bid >> 5;
    const int slab = (bid & 31) * 16;
    const int t = threadIdx.x;
    const int wv = t >> 6, lane = t & 63;
    const int lr = lane & 15, lg = lane >> 4, lk = lg * 8;
    const int c0 = wv * 64;

    f32x4 acc[4];
    oprojln_phase(ao16, WoT, bo, gamma, beta, xa, slab, c0, wv, lr, lg, lk, red, acc);
#pragma unroll
    for (int j = 0; j < 4; ++j) {
        const int col = c0 + j * 16 + lr;
#pragma unroll
        for (int rg = 0; rg < 4; ++rg) {
            if (p6 == 0) xb[(slab + lg * 4 + rg) * HDIM + col] = acc[j][rg];
            xpan[(lg * 4 + rg) * XPS + col] = f2bf(acc[j][rg]);
        }
    }
    __syncthreads();
    const int prob = p6 >> 1, ch = p6 & 1;
    const ushort* Wt = (prob == 0) ? WqT : (prob == 1) ? WkT : WvT;
    const float*  bb = (prob == 0) ? bq  : (prob == 1) ? bk  : bv;
    qkv_one2(xpan, Wt, bb, prob, slab, ch * 128 + wv * 32, lr, lg, lk,
             q16, k16, vT16);
}

// ---------------------------------------------------------------------------
// oprojmlpU: 128 blocks. p4 = bid>>5: p = p4>>1, ch = p4&1. U1/U2 bf16 out.
// ---------------------------------------------------------------------------
__global__ __launch_bounds__(256) void oprojmlpU(
    const ushort* __restrict__ ao16, const ushort* __restrict__ WoT,
    const float* __restrict__ bo, const float* __restrict__ gamma,
    const float* __restrict__ beta,
    const ushort* __restrict__ m1WT, const float* __restrict__ m1b,
    const ushort* __restrict__ m2WT, const float* __restrict__ m2b,
    const ushort* __restrict__ cW1aT, const float* __restrict__ cb1,
    const ushort* __restrict__ cW1bT,
    const float* __restrict__ xb, ushort* __restrict__ U1b,
    ushort* __restrict__ U2b)
{
    __shared__ __align__(16) ushort xpan[16 * XPS];
    __shared__ __align__(16) ushort opan[16 * XPS];
    __shared__ float red[4][16];
    const int bid  = blockIdx.x;
    const int p4   = bid >> 5;
    const int p    = p4 >> 1, ch = p4 & 1;
    const int slab = (bid & 31) * 16;
    const int t = threadIdx.x;
    const int wv = t >> 6, lane = t & 63;
    const int lr = lane & 15, lg = lane >> 4, lk = lg * 8;
    const int c0 = wv * 64;

    f32x4 acc[4];
    oprojln_phase(ao16, WoT, bo, gamma, beta, xb, slab, c0, wv, lr, lg, lk, red, acc);
#pragma unroll
    for (int j = 0; j < 4; ++j) {
        const int col = c0 + j * 16 + lr;
#pragma unroll
        for (int rg = 0; rg < 4; ++rg)
            xpan[(lg * 4 + rg) * XPS + col] = f2bf(acc[j][rg]);
    }
    __syncthreads();

    {   // phase 2: full o_p panel
        const ushort* Wt = p ? m2WT : m1WT;
        const float*  bb = p ? m2b  : m1b;
        const ushort* Ap = xpan + lr * XPS + lk;
        f32x4 a2[4];
#pragma unroll
        for (int j = 0; j < 4; ++j) a2[j] = (f32x4){0.f, 0.f, 0.f, 0.f};
#pragma unroll
        for (int ks = 0; ks < 8; ++ks) {
            const bf16x8 a = *(const bf16x8*)&Ap[ks * 32];
#pragma unroll
            for (int j = 0; j < 4; ++j) {
                const bf16x8 b = *(const bf16x8*)&Wt[(c0 + j * 16 + lr) * HDIM + ks * 32 + lk];
                a2[j] = __builtin_amdgcn_mfma_f32_16x16x32_bf16(a, b, a2[j], 0, 0, 0);
            }
        }
#pragma unroll
        for (int j = 0; j < 4; ++j) {
            const int col = c0 + j * 16 + lr;
            const float bbv = bb[col];
#pragma unroll
            for (int rg = 0; rg < 4; ++rg)
                opan[(lg * 4 + rg) * XPS + col] = f2bf(fmaxf(a2[j][rg] + bbv, 0.f));
        }
    }
    __syncthreads();

    {   // phase 3: U_p, col-half ch (wave = 2 col-groups), bf16 output
        const ushort* Wt = p ? cW1bT : cW1aT;
        ushort* U        = p ? U2b : U1b;
        const int cb     = ch * 128 + wv * 32;
        const ushort* Ao = opan + lr * XPS + lk;
        f32x4 a2[2];
        a2[0] = (f32x4){0.f, 0.f, 0.f, 0.f};
        a2[1] = (f32x4){0.f, 0.f, 0.f, 0.f};
#pragma unroll
        for (int ks = 0; ks < 8; ++ks) {
            const bf16x8 a = *(const bf16x8*)&Ao[ks * 32];
#pragma unroll
            for (int j = 0; j < 2; ++j) {
                const bf16x8 b = *(const bf16x8*)&Wt[(cb + j * 16 + lr) * HDIM + ks * 32 + lk];
                a2[j] = __builtin_amdgcn_mfma_f32_16x16x32_bf16(a, b, a2[j], 0, 0, 0);
            }
        }
#pragma unroll
        for (int j = 0; j < 2; ++j) {
            const int col = cb + j * 16 + lr;
            const float bbv = (p == 0) ? cb1[col] : 0.f;
#pragma unroll
            for (int rg = 0; rg < 4; ++rg)
                U[(slab + lg * 4 + rg) * HDIM + col] = f2bf(a2[j][rg] + bbv);
        }
    }
}

// ---------------------------------------------------------------------------
// pair_cls: 32x32 tile, 2x2/thread. bf16 LDS panels, f32 w2. (r13 proven)
// ---------------------------------------------------------------------------
__global__ __launch_bounds__(256) void pair_cls(const ushort* __restrict__ U1b,
                                                const ushort* __restrict__ U2b,
                                                const float* __restrict__ W2,
                                                const float* __restrict__ b2,
                                                float* __restrict__ out)
{
    __shared__ __align__(16) ushort u1s[32][264];
    __shared__ __align__(16) ushort u2s[32][264];
    __shared__ __align__(16) float w2s[256];
    const int t  = threadIdx.x;
    const int n0 = blockIdx.y * 32, m0 = blockIdx.x * 32;

#pragma unroll
    for (int u = 0; u < 4; ++u) {
        const int i = t + u * 256;
        const int r = i >> 5, c8 = i & 31;
        *(uint4*)&u1s[r][c8 * 8] = *(const uint4*)&U1b[(n0 + r) * HDIM + c8 * 8];
        *(uint4*)&u2s[r][c8 * 8] = *(const uint4*)&U2b[(m0 + r) * HDIM + c8 * 8];
    }
    if (t < 64) *(float4*)&w2s[t * 4] = *(const float4*)&W2[t * 4];
    __syncthreads();

    const int tx = t & 15, ty = t >> 4;
    const ushort* r0 = &u1s[ty * 2][0];
    const ushort* r1 = &u1s[ty * 2 + 1][0];
    const ushort* c0 = &u2s[tx * 2][0];
    const ushort* c1 = &u2s[tx * 2 + 1][0];
    float acc[2][2] = {};

#define RT(A, B) fmaxf((A) + (B), 0.f)
    for (int h8 = 0; h8 < 32; ++h8) {
        const uint4 A0 = *(const uint4*)&r0[h8 * 8];
        const uint4 A1 = *(const uint4*)&r1[h8 * 8];
        const uint4 B0 = *(const uint4*)&c0[h8 * 8];
        const uint4 B1 = *(const uint4*)&c1[h8 * 8];
        const float4 w0 = *(const float4*)&w2s[h8 * 8];
        const float4 w1 = *(const float4*)&w2s[h8 * 8 + 4];
        const float warr[8] = {w0.x, w0.y, w0.z, w0.w, w1.x, w1.y, w1.z, w1.w};
#pragma unroll
        for (int q = 0; q < 4; ++q) {
            const unsigned a0u = ((const unsigned*)&A0)[q];
            const unsigned a1u = ((const unsigned*)&A1)[q];
            const unsigned b0u = ((const unsigned*)&B0)[q];
            const unsigned b1u = ((const unsigned*)&B1)[q];
            const float a0l = bf_lo(a0u), a0h = bf_hi(a0u);
            const float a1l = bf_lo(a1u), a1h = bf_hi(a1u);
            const float b0l = bf_lo(b0u), b0h = bf_hi(b0u);
            const float b1l = bf_lo(b1u), b1h = bf_hi(b1u);
            const float wl = warr[q * 2], wh = warr[q * 2 + 1];
            acc[0][0] += RT(a0l, b0l) * wl + RT(a0h, b0h) * wh;
            acc[0][1] += RT(a0l, b1l) * wl + RT(a0h, b1h) * wh;
            acc[1][0] += RT(a1l, b0l) * wl + RT(a1h, b0h) * wh;
            acc[1][1] += RT(a1l, b1l) * wl + RT(a1h, b1h) * wh;
        }
    }
#undef RT

    const float bbv = b2[0];
#pragma unroll
    for (int ii = 0; ii < 2; ++ii)
#pragma unroll
        for (int jj = 0; jj < 2; ++jj) {
            const float val = acc[ii][jj] + bbv;
            const int n = n0 + ty * 2 + ii;
            const int m = m0 + tx * 2 + jj;
#pragma unroll
            for (int tl = 0; tl < TLEN; ++tl)
                out[tl * NTOK * NTOK + n * NTOK + m] = val;
        }
}

// ---------------------------------------------------------------------------
extern "C" void kernel_launch(void* const* d_in, const int* in_sizes, int n_in,
                              void* d_out, int out_size, void* d_ws, size_t ws_size,
                              hipStream_t stream)
{
    const float* hs   = (const float*)d_in[0];
    const float* qf   = hs + 5 * NTOK * HDIM;
    const float* alp  = (const float*)d_in[1];
    const float* pl   = alp + 5 * NTOK * 33;
    const float* fc_W = (const float*)d_in[2];
    const float* fc_b = (const float*)d_in[3];
    const float* Wq   = (const float*)d_in[4];
    const float* bq   = (const float*)d_in[5];
    const float* Wk   = (const float*)d_in[6];
    const float* bk   = (const float*)d_in[7];
    const float* Wv   = (const float*)d_in[8];
    const float* bv   = (const float*)d_in[9];
    const float* Wo   = (const float*)d_in[10];
    const float* bo   = (const float*)d_in[11];
    const float* lng  = (const float*)d_in[12];
    const float* lnb  = (const float*)d_in[13];
    const float* m1W  = (const float*)d_in[14];
    const float* m1b  = (const float*)d_in[15];
    const float* m2W  = (const float*)d_in[16];
    const float* m2b  = (const float*)d_in[17];
    const float* cW1  = (const float*)d_in[18];
    const float* cb1  = (const float*)d_in[19];
    const float* cW2  = (const float*)d_in[20];
    const float* cb2  = (const float*)d_in[21];
    float* out = (float*)d_out;

    const int NN  = NTOK * NTOK;
    const int NH_ = NTOK * HDIM;
    float* ws     = (float*)d_ws;
    float* dist   = ws;                       // NN
    float* dwraw  = ws + NN;                  // NN
    float* inv_cs = ws + 2 * NN;              // 512
    float* xa     = ws + 2 * NN + 512;        // NH
    float* xb     = xa + NH_;                 // NH
    ushort* u16   = (ushort*)(xb + NH_);
    ushort* wpk   = u16;                      // 13 * WSZ
    ushort* q16   = wpk + 13 * WSZ;           // NH
    ushort* k16   = q16 + NH_;                // NH
    ushort* vT16  = k16 + NH_;                // NH ([d][m])
    ushort* ao16  = vT16 + NH_;               // NH
    ushort* U1b   = ao16 + NH_;               // NH
    ushort* U2b   = U1b + NH_;                // NH

    PKArg pk;
    pk.w[0]  = fc_W;
    pk.w[1]  = Wq;  pk.w[2]  = Wq + WSZ;
    pk.w[3]  = Wk;  pk.w[4]  = Wk + WSZ;
    pk.w[5]  = Wv;  pk.w[6]  = Wv + WSZ;
    pk.w[7]  = Wo;  pk.w[8]  = Wo + WSZ;
    pk.w[9]  = m1W; pk.w[10] = m2W;
    pk.w[11] = cW1; pk.w[12] = cW1 + WSZ;
    pk.pl = pl;
    pk.wpk = wpk;
    pk.dist = dist; pk.dwraw = dwraw; pk.inv_cs = inv_cs;
    pack_kernel<<<216, 256, 0, stream>>>(pk);

    // fc (replicated x6) + qkv (L0)
    fcqkv<<<192, 256, 0, stream>>>(
        qf, wpk + 0 * WSZ, fc_b,
        wpk + 1 * WSZ, bq, wpk + 3 * WSZ, bk, wpk + 5 * WSZ, bv,
        xa, q16, k16, vT16);

    attn_fused<<<128, 512, 0, stream>>>(q16, k16, vT16, dist, dwraw, inv_cs, ao16);

    // oproj+LN (L0, replicated x6) -> qkv (L1)
    oprojqkv<<<192, 256, 0, stream>>>(
        ao16, wpk + 7 * WSZ, bo, lng, lnb,
        wpk + 2 * WSZ, bq + HDIM, wpk + 4 * WSZ, bk + HDIM,
        wpk + 6 * WSZ, bv + HDIM,
        xa, xb, q16, k16, vT16);

    attn_fused<<<128, 512, 0, stream>>>(q16, k16, vT16, dist, dwraw, inv_cs, ao16);

    // oproj+LN (L1, replicated x4) -> mlp_p -> U_p (bf16 out)
    oprojmlpU<<<128, 256, 0, stream>>>(
        ao16, wpk + 8 * WSZ, bo + HDIM, lng + HDIM, lnb + HDIM,
        wpk + 9 * WSZ, m1b, wpk + 10 * WSZ, m2b,
        wpk + 11 * WSZ, cb1, wpk + 12 * WSZ,
        xb, U1b, U2b);

    pair_cls<<<dim3(16, 16), 256, 0, stream>>>(U1b, U2b, cW2, cb2, out);
}

// Round 17
// 92.372 us; speedup vs baseline: 1.1229x; 1.0315x over previous
//
#include <hip/hip_runtime.h>
#include <math.h>

// ---------------------------------------------------------------------------
// SpatialProximityHead on MI355X — round 16: r16 + critical-path pack split.
// pack1 packs only mats {0,1,3,5} (64 blocks); remaining 9 mats + dist prep
// ride as aux blocks inside fcqkv (344 blocks). 7 dispatches.
// ---------------------------------------------------------------------------

#define NTOK 512
#define HDIM 256
#define DKH  64
#define NHEAD 4
#define TLEN 6
#define WSZ  65536
#define PSTR 520   // attn P_lds ushort stride
#define XPS  264   // LDS panel ushort stride

typedef __attribute__((ext_vector_type(8))) short bf16x8;
typedef __attribute__((ext_vector_type(4))) float f32x4;

__device__ __forceinline__ ushort f2bf(float f)
{
    unsigned u = __builtin_bit_cast(unsigned, f);
    u += 0x7FFFu + ((u >> 16) & 1u);     // RNE
    return (ushort)(u >> 16);
}
__device__ __forceinline__ float bf_lo(unsigned u)
{
    return __builtin_bit_cast(float, u << 16);
}
__device__ __forceinline__ float bf_hi(unsigned u)
{
    return __builtin_bit_cast(float, u & 0xFFFF0000u);
}

// ---------------------------------------------------------------------------
// pack_tile: one 64x64 transpose tile of a 256x256 weight -> [col][k] bf16.
// smu: >= 64*72 ushorts.
// ---------------------------------------------------------------------------
__device__ void pack_tile(const float* __restrict__ W, ushort* __restrict__ dst,
                          int tile, ushort* smu)
{
    const int k0 = (tile >> 2) * 64;
    const int c0 = (tile & 3) * 64;
    const int t  = threadIdx.x;
#pragma unroll
    for (int j = 0; j < 4; ++j) {
        const int i  = t + j * 256;
        const int r  = i >> 4, c4 = i & 15;
        const float4 v4 = *(const float4*)&W[(k0 + r) * HDIM + c0 + c4 * 4];
        smu[(c4 * 4 + 0) * 72 + r] = f2bf(v4.x);
        smu[(c4 * 4 + 1) * 72 + r] = f2bf(v4.y);
        smu[(c4 * 4 + 2) * 72 + r] = f2bf(v4.z);
        smu[(c4 * 4 + 3) * 72 + r] = f2bf(v4.w);
    }
    __syncthreads();
#pragma unroll
    for (int j = 0; j < 2; ++j) {
        const int i  = t + j * 256;
        const int cr = i >> 3, kk = i & 7;
        const uint4 v = *(const uint4*)&smu[cr * 72 + kk * 8];
        *(uint4*)&dst[(c0 + cr) * HDIM + k0 + kk * 8] = v;
    }
}

// dist/dwraw/inv_cs prep item: 64 m-cols, 256 threads. smf >= 1792 floats.
__device__ void dist_item(const float* __restrict__ pl, float* __restrict__ dist,
                          float* __restrict__ dwraw, float* __restrict__ inv_cs,
                          int item, float* smf)
{
    float* qe  = smf;            // [512][3]
    float* red = smf + 1536;     // [4][64]
    const int t = threadIdx.x;
    for (int i = t; i < 512; i += 256) {
        qe[i * 3 + 0] = pl[i * 33 + 30];
        qe[i * 3 + 1] = pl[i * 33 + 31];
        qe[i * 3 + 2] = pl[i * 33 + 32];
    }
    __syncthreads();
    const int m   = item * 64 + (t & 63);
    const int nch = t >> 6;
    const float kx = pl[m * 33 + 0], ky = pl[m * 33 + 1], kz = pl[m * 33 + 2];
    float cs = 0.f;
    for (int n = nch * 128; n < nch * 128 + 128; ++n) {
        const float dx = kx - qe[n * 3 + 0];
        const float dy = ky - qe[n * 3 + 1];
        const float dz = kz - qe[n * 3 + 2];
        const float dd = sqrtf(dx * dx + dy * dy + dz * dz);
        const float w  = 1.0f / (dd + 0.01f);
        dist[n * NTOK + m]  = dd;
        dwraw[n * NTOK + m] = w;
        cs += w;
    }
    red[nch * 64 + (t & 63)] = cs;
    __syncthreads();
    if (t < 64)
        inv_cs[item * 64 + t] =
            1.0f / (red[t] + red[64 + t] + red[128 + t] + red[192 + t]);
}

// ---------------------------------------------------------------------------
// pack1: critical-path mats only: {fc, WqL0, WkL0, WvL0} = 64 blocks.
// ---------------------------------------------------------------------------
struct PK1 { const float* w[4]; int mat[4]; ushort* wpk; };

__global__ __launch_bounds__(256) void pack1_kernel(PK1 p)
{
    __shared__ __align__(16) ushort smu[64 * 72];
    const int mi = blockIdx.x >> 4;
    pack_tile(p.w[mi], p.wpk + p.mat[mi] * WSZ, blockIdx.x & 15, smu);
}

// ---------------------------------------------------------------------------
// qkv_one2: one qkv problem, 2 col-groups starting at c0. prob: 0->q16,
// 1->k16 (row-major), 2->vT16 (transposed).
// ---------------------------------------------------------------------------
__device__ __forceinline__ void qkv_one2(
    const ushort* __restrict__ xpan, const ushort* __restrict__ Wt,
    const float* __restrict__ bb, int prob,
    int slab, int c0, int lr, int lg, int lk,
    ushort* __restrict__ q16, ushort* __restrict__ k16,
    ushort* __restrict__ vT16)
{
    const ushort* Ap = xpan + lr * XPS + lk;
    f32x4 acc[2];
    acc[0] = (f32x4){0.f, 0.f, 0.f, 0.f};
    acc[1] = (f32x4){0.f, 0.f, 0.f, 0.f};
#pragma unroll
    for (int ks = 0; ks < 8; ++ks) {
        const bf16x8 a = *(const bf16x8*)&Ap[ks * 32];
#pragma unroll
        for (int j = 0; j < 2; ++j) {
            const bf16x8 b = *(const bf16x8*)&Wt[(c0 + j * 16 + lr) * HDIM + ks * 32 + lk];
            acc[j] = __builtin_amdgcn_mfma_f32_16x16x32_bf16(a, b, acc[j], 0, 0, 0);
        }
    }
#pragma unroll
    for (int j = 0; j < 2; ++j) {
        const int col = c0 + j * 16 + lr;
        const float bv2 = bb[col];
        if (prob < 2) {
            ushort* dst = (prob == 0) ? q16 : k16;
#pragma unroll
            for (int rg = 0; rg < 4; ++rg)
                dst[(slab + lg * 4 + rg) * HDIM + col] = f2bf(acc[j][rg] + bv2);
        } else {
            ushort4 s = {f2bf(acc[j][0] + bv2), f2bf(acc[j][1] + bv2),
                         f2bf(acc[j][2] + bv2), f2bf(acc[j][3] + bv2)};
            *(ushort4*)&vT16[col * NTOK + slab + lg * 4] = s;
        }
    }
}

// ---------------------------------------------------------------------------
// fcqkv: 344 blocks.
//  0-191: p6 = bid>>5: prob = p6>>1, ch = p6&1; fc (replicated) -> qkv L0.
//  192-335: pack tiles for 9 deferred mats.  336-343: dist prep items.
// ---------------------------------------------------------------------------
struct FQAux { const float* w[9]; int mat[9]; };

__global__ __launch_bounds__(256) void fcqkv(
    const float* __restrict__ qf, const ushort* __restrict__ fcWt,
    const float* __restrict__ fcb,
    const ushort* __restrict__ WqT, const float* __restrict__ bq,
    const ushort* __restrict__ WkT, const float* __restrict__ bk,
    const ushort* __restrict__ WvT, const float* __restrict__ bv,
    float* __restrict__ xa, ushort* __restrict__ q16,
    ushort* __restrict__ k16, ushort* __restrict__ vT16,
    FQAux aux, ushort* __restrict__ wpk, const float* __restrict__ pl,
    float* __restrict__ dist, float* __restrict__ dwraw,
    float* __restrict__ inv_cs)
{
    __shared__ __align__(16) ushort smu[64 * 72];   // 9216 B, union buffer
    const int bid  = blockIdx.x;

    if (bid >= 192) {
        const int ib = bid - 192;
        if (ib < 144) {
            pack_tile(aux.w[ib >> 4], wpk + aux.mat[ib >> 4] * WSZ, ib & 15, smu);
        } else {
            dist_item(pl, dist, dwraw, inv_cs, ib - 144, (float*)smu);
        }
        return;
    }

    ushort* xpan = smu;                  // 16*XPS = 4224 <= 4608 ushorts
    const int p6   = bid >> 5;
    const int slab = (bid & 31) * 16;
    const int t = threadIdx.x;
    const int wv = t >> 6, lane = t & 63;
    const int lr = lane & 15, lg = lane >> 4, lk = lg * 8;
    const int c0 = wv * 64;

    {   // phase 1: fc (replicated)
        f32x4 acc[4];
#pragma unroll
        for (int j = 0; j < 4; ++j) acc[j] = (f32x4){0.f, 0.f, 0.f, 0.f};
        const float* Aq = qf + (slab + lr) * HDIM + lk;
#pragma unroll
        for (int ks = 0; ks < 8; ++ks) {
            const float4 a0 = *(const float4*)&Aq[ks * 32];
            const float4 a1 = *(const float4*)&Aq[ks * 32 + 4];
            bf16x8 a;
            a[0] = (short)f2bf(a0.x); a[1] = (short)f2bf(a0.y);
            a[2] = (short)f2bf(a0.z); a[3] = (short)f2bf(a0.w);
            a[4] = (short)f2bf(a1.x); a[5] = (short)f2bf(a1.y);
            a[6] = (short)f2bf(a1.z); a[7] = (short)f2bf(a1.w);
#pragma unroll
            for (int j = 0; j < 4; ++j) {
                const bf16x8 b = *(const bf16x8*)&fcWt[(c0 + j * 16 + lr) * HDIM + ks * 32 + lk];
                acc[j] = __builtin_amdgcn_mfma_f32_16x16x32_bf16(a, b, acc[j], 0, 0, 0);
            }
        }
#pragma unroll
        for (int j = 0; j < 4; ++j) {
            const int col = c0 + j * 16 + lr;
            const float bbv = fcb[col];
#pragma unroll
            for (int rg = 0; rg < 4; ++rg) {
                const float o = fmaxf(acc[j][rg] + bbv, 0.f);
                if (p6 == 0) xa[(slab + lg * 4 + rg) * HDIM + col] = o;
                xpan[(lg * 4 + rg) * XPS + col] = f2bf(o);
            }
        }
    }
    __syncthreads();
    const int prob = p6 >> 1, ch = p6 & 1;
    const ushort* Wt = (prob == 0) ? WqT : (prob == 1) ? WkT : WvT;
    const float*  bb = (prob == 0) ? bq  : (prob == 1) ? bk  : bv;
    qkv_one2(xpan, Wt, bb, prob, slab, ch * 128 + wv * 32, lr, lg, lk,
             q16, k16, vT16);
}

// ---------------------------------------------------------------------------
// attn_fused: 128 blocks x 512 thr. QK^T wave = key-slice of 64;
// PV wave = (db = wv&3, kh = wv>>2), V fragments prefetched before softmax.
// ---------------------------------------------------------------------------
__global__ __launch_bounds__(512) void attn_fused(
    const ushort* __restrict__ q16, const ushort* __restrict__ k16,
    const ushort* __restrict__ vT16, const float* __restrict__ dist,
    const float* __restrict__ dwraw, const float* __restrict__ inv_cs,
    ushort* __restrict__ ao16)
{
    __shared__ __align__(16) ushort P_lds[16 * PSTR];
    __shared__ __align__(16) float exch[2][16][64];
    __shared__ float rmax[8][16];
    __shared__ float psums[8][16];

    const int bid = blockIdx.x;
    const int h  = bid >> 5;
    const int n0 = (bid & 31) * 16;
    const int t  = threadIdx.x;
    const int wv = t >> 6, lane = t & 63;
    const int lr = lane & 15, lg = lane >> 4, lk = lg * 8;
    const int mW = wv * 64;

    const ushort* Qrow = q16 + (n0 + lr) * HDIM + h * DKH + lk;
    const bf16x8 a0 = *(const bf16x8*)&Qrow[0];
    const bf16x8 a1 = *(const bf16x8*)&Qrow[32];

    f32x4 accs[4];
#pragma unroll
    for (int cg = 0; cg < 4; ++cg) accs[cg] = (f32x4){0.f, 0.f, 0.f, 0.f};
#pragma unroll
    for (int cg = 0; cg < 4; ++cg) {
        const ushort* Brow = k16 + (mW + cg * 16 + lr) * HDIM + h * DKH + lk;
        accs[cg] = __builtin_amdgcn_mfma_f32_16x16x32_bf16(
            a0, *(const bf16x8*)&Brow[0], accs[cg], 0, 0, 0);
        accs[cg] = __builtin_amdgcn_mfma_f32_16x16x32_bf16(
            a1, *(const bf16x8*)&Brow[32], accs[cg], 0, 0, 0);
    }

    // prefetch V fragments (independent of softmax)
    const int db = wv & 3, kh = wv >> 2;
    const ushort* Vrow = vT16 + (h * DKH + db * 16 + lr) * NTOK + kh * 256 + lk;
    bf16x8 vfrag[8];
#pragma unroll
    for (int c = 0; c < 8; ++c)
        vfrag[c] = *(const bf16x8*)&Vrow[c * 32];

    float s[4][4];
#pragma unroll
    for (int cg = 0; cg < 4; ++cg) {
        const int m = mW + cg * 16 + lr;
        const float ic = (h == 0) ? inv_cs[m] : 0.f;
#pragma unroll
        for (int rg = 0; rg < 4; ++rg) {
            const int n = n0 + lg * 4 + rg;
            float b = 0.f;
            if (h == 0)      b = dwraw[n * NTOK + m] * ic;
            else if (h == 1) b = -dist[n * NTOK + m];
            s[cg][rg] = accs[cg][rg] * 0.125f + b;
        }
    }

    float mx[4];
#pragma unroll
    for (int rg = 0; rg < 4; ++rg) {
        float m = fmaxf(fmaxf(s[0][rg], s[1][rg]), fmaxf(s[2][rg], s[3][rg]));
#pragma unroll
        for (int o = 1; o < 16; o <<= 1) m = fmaxf(m, __shfl_xor(m, o));
        mx[rg] = m;
    }
    if (lr == 0)
#pragma unroll
        for (int rg = 0; rg < 4; ++rg) rmax[wv][lg * 4 + rg] = mx[rg];
    __syncthreads();
    float mxf[4];
#pragma unroll
    for (int rg = 0; rg < 4; ++rg) {
        const int row = lg * 4 + rg;
        float m = rmax[0][row];
#pragma unroll
        for (int w = 1; w < 8; ++w) m = fmaxf(m, rmax[w][row]);
        mxf[rg] = m;
    }

    float ps[4] = {0.f, 0.f, 0.f, 0.f};
#pragma unroll
    for (int cg = 0; cg < 4; ++cg)
#pragma unroll
        for (int rg = 0; rg < 4; ++rg) {
            const float e = __expf(s[cg][rg] - mxf[rg]);
            ps[rg] += e;
            P_lds[(lg * 4 + rg) * PSTR + mW + cg * 16 + lr] = f2bf(e);
        }
#pragma unroll
    for (int rg = 0; rg < 4; ++rg) {
#pragma unroll
        for (int o = 1; o < 16; o <<= 1) ps[rg] += __shfl_xor(ps[rg], o);
    }
    if (lr == 0)
#pragma unroll
        for (int rg = 0; rg < 4; ++rg) psums[wv][lg * 4 + rg] = ps[rg];
    __syncthreads();

    {
        f32x4 acco = (f32x4){0.f, 0.f, 0.f, 0.f};
        const ushort* Prow = P_lds + lr * PSTR + kh * 256 + lk;
#pragma unroll
        for (int c = 0; c < 8; ++c) {
            const bf16x8 pa = *(const bf16x8*)&Prow[c * 32];
            acco = __builtin_amdgcn_mfma_f32_16x16x32_bf16(pa, vfrag[c], acco, 0, 0, 0);
        }
#pragma unroll
        for (int rg = 0; rg < 4; ++rg)
            exch[kh][lg * 4 + rg][db * 16 + lr] = acco[rg];
    }
    __syncthreads();

    if (t < 256) {
        const int r = t >> 4, d4 = t & 15;
        f32x4 sum = *(const f32x4*)&exch[0][r][d4 * 4];
        sum += *(const f32x4*)&exch[1][r][d4 * 4];
        float den = 0.f;
#pragma unroll
        for (int w = 0; w < 8; ++w) den += psums[w][r];
        const float inv = 1.0f / den;
        ushort4 o = {f2bf(sum.x * inv), f2bf(sum.y * inv),
                     f2bf(sum.z * inv), f2bf(sum.w * inv)};
        *(ushort4*)&ao16[(n0 + r) * HDIM + h * DKH + d4 * 4] = o;
    }
}

// ---------------------------------------------------------------------------
// oproj+LN phase (proven): normalized values left in acc.
// ---------------------------------------------------------------------------
__device__ __forceinline__ void oprojln_phase(
    const ushort* __restrict__ ao16, const ushort* __restrict__ WoT,
    const float* __restrict__ bo, const float* __restrict__ gamma,
    const float* __restrict__ beta, const float* __restrict__ x,
    int slab, int c0, int wv, int lr, int lg, int lk,
    float red[4][16], f32x4 acc[4])
{
    const ushort* Arow = ao16 + (slab + lr) * HDIM + lk;
#pragma unroll
    for (int j = 0; j < 4; ++j) acc[j] = (f32x4){0.f, 0.f, 0.f, 0.f};
#pragma unroll
    for (int ks = 0; ks < 8; ++ks) {
        const bf16x8 a = *(const bf16x8*)&Arow[ks * 32];
#pragma unroll
        for (int j = 0; j < 4; ++j) {
            const bf16x8 b = *(const bf16x8*)&WoT[(c0 + j * 16 + lr) * HDIM + ks * 32 + lk];
            acc[j] = __builtin_amdgcn_mfma_f32_16x16x32_bf16(a, b, acc[j], 0, 0, 0);
        }
    }
#pragma unroll
    for (int j = 0; j < 4; ++j) {
        const int col = c0 + j * 16 + lr;
        const float bc = bo[col];
#pragma unroll
        for (int rg = 0; rg < 4; ++rg)
            acc[j][rg] += bc + x[(slab + lg * 4 + rg) * HDIM + col];
    }

    float sm[4];
#pragma unroll
    for (int rg = 0; rg < 4; ++rg) {
        float s = 0.f;
#pragma unroll
        for (int j = 0; j < 4; ++j) s += acc[j][rg];
#pragma unroll
        for (int o = 1; o < 16; o <<= 1) s += __shfl_xor(s, o);
        sm[rg] = s;
    }
    if (lr == 0)
#pragma unroll
        for (int rg = 0; rg < 4; ++rg) red[wv][lg * 4 + rg] = sm[rg];
    __syncthreads();
    float mean[4];
#pragma unroll
    for (int rg = 0; rg < 4; ++rg) {
        const int row = lg * 4 + rg;
        mean[rg] = (red[0][row] + red[1][row] + red[2][row] + red[3][row]) * (1.f / 256.f);
    }
    __syncthreads();

#pragma unroll
    for (int rg = 0; rg < 4; ++rg) {
        float s2 = 0.f;
#pragma unroll
        for (int j = 0; j < 4; ++j) {
            const float c = acc[j][rg] - mean[rg];
            s2 += c * c;
        }
#pragma unroll
        for (int o = 1; o < 16; o <<= 1) s2 += __shfl_xor(s2, o);
        sm[rg] = s2;
    }
    if (lr == 0)
#pragma unroll
        for (int rg = 0; rg < 4; ++rg) red[wv][lg * 4 + rg] = sm[rg];
    __syncthreads();
    float rstd[4];
#pragma unroll
    for (int rg = 0; rg < 4; ++rg) {
        const int row = lg * 4 + rg;
        const float var = (red[0][row] + red[1][row] + red[2][row] + red[3][row]) * (1.f / 256.f);
        rstd[rg] = rsqrtf(var + 1e-5f);
    }
#pragma unroll
    for (int j = 0; j < 4; ++j) {
        const int col = c0 + j * 16 + lr;
        const float gg = gamma[col], bv = beta[col];
#pragma unroll
        for (int rg = 0; rg < 4; ++rg)
            acc[j][rg] = (acc[j][rg] - mean[rg]) * rstd[rg] * gg + bv;
    }
}

// ---------------------------------------------------------------------------
// oprojqkv: 192 blocks. p6 = bid>>5: prob = p6>>1, ch = p6&1.
// ---------------------------------------------------------------------------
__global__ __launch_bounds__(256) void oprojqkv(
    const ushort* __restrict__ ao16, const ushort* __restrict__ WoT,
    const float* __restrict__ bo, const float* __restrict__ gamma,
    const float* __restrict__ beta,
    const ushort* __restrict__ WqT, const float* __restrict__ bq,
    const ushort* __restrict__ WkT, const float* __restrict__ bk,
    const ushort* __restrict__ WvT, const float* __restrict__ bv,
    const float* __restrict__ xa, float* __restrict__ xb,
    ushort* __restrict__ q16, ushort* __restrict__ k16,
    ushort* __restrict__ vT16)
{
    __shared__ __align__(16) ushort xpan[16 * XPS];
    __shared__ float red[4][16];
    const int bid  = blockIdx.x;
    const int p6   = bid >> 5;
    const int slab = (bid & 31) * 16;
    const int t = threadIdx.x;
    const int wv = t >> 6, lane = t & 63;
    const int lr = lane & 15, lg = lane >> 4, lk = lg * 8;
    const int c0 = wv * 64;

    f32x4 acc[4];
    oprojln_phase(ao16, WoT, bo, gamma, beta, xa, slab, c0, wv, lr, lg, lk, red, acc);
#pragma unroll
    for (int j = 0; j < 4; ++j) {
        const int col = c0 + j * 16 + lr;
#pragma unroll
        for (int rg = 0; rg < 4; ++rg) {
            if (p6 == 0) xb[(slab + lg * 4 + rg) * HDIM + col] = acc[j][rg];
            xpan[(lg * 4 + rg) * XPS + col] = f2bf(acc[j][rg]);
        }
    }
    __syncthreads();
    const int prob = p6 >> 1, ch = p6 & 1;
    const ushort* Wt = (prob == 0) ? WqT : (prob == 1) ? WkT : WvT;
    const float*  bb = (prob == 0) ? bq  : (prob == 1) ? bk  : bv;
    qkv_one2(xpan, Wt, bb, prob, slab, ch * 128 + wv * 32, lr, lg, lk,
             q16, k16, vT16);
}

// ---------------------------------------------------------------------------
// oprojmlpU: 128 blocks. p4 = bid>>5: p = p4>>1, ch = p4&1. U1/U2 bf16 out.
// ---------------------------------------------------------------------------
__global__ __launch_bounds__(256) void oprojmlpU(
    const ushort* __restrict__ ao16, const ushort* __restrict__ WoT,
    const float* __restrict__ bo, const float* __restrict__ gamma,
    const float* __restrict__ beta,
    const ushort* __restrict__ m1WT, const float* __restrict__ m1b,
    const ushort* __restrict__ m2WT, const float* __restrict__ m2b,
    const ushort* __restrict__ cW1aT, const float* __restrict__ cb1,
    const ushort* __restrict__ cW1bT,
    const float* __restrict__ xb, ushort* __restrict__ U1b,
    ushort* __restrict__ U2b)
{
    __shared__ __align__(16) ushort xpan[16 * XPS];
    __shared__ __align__(16) ushort opan[16 * XPS];
    __shared__ float red[4][16];
    const int bid  = blockIdx.x;
    const int p4   = bid >> 5;
    const int p    = p4 >> 1, ch = p4 & 1;
    const int slab = (bid & 31) * 16;
    const int t = threadIdx.x;
    const int wv = t >> 6, lane = t & 63;
    const int lr = lane & 15, lg = lane >> 4, lk = lg * 8;
    const int c0 = wv * 64;

    f32x4 acc[4];
    oprojln_phase(ao16, WoT, bo, gamma, beta, xb, slab, c0, wv, lr, lg, lk, red, acc);
#pragma unroll
    for (int j = 0; j < 4; ++j) {
        const int col = c0 + j * 16 + lr;
#pragma unroll
        for (int rg = 0; rg < 4; ++rg)
            xpan[(lg * 4 + rg) * XPS + col] = f2bf(acc[j][rg]);
    }
    __syncthreads();

    {   // phase 2: full o_p panel
        const ushort* Wt = p ? m2WT : m1WT;
        const float*  bb = p ? m2b  : m1b;
        const ushort* Ap = xpan + lr * XPS + lk;
        f32x4 a2[4];
#pragma unroll
        for (int j = 0; j < 4; ++j) a2[j] = (f32x4){0.f, 0.f, 0.f, 0.f};
#pragma unroll
        for (int ks = 0; ks < 8; ++ks) {
            const bf16x8 a = *(const bf16x8*)&Ap[ks * 32];
#pragma unroll
            for (int j = 0; j < 4; ++j) {
                const bf16x8 b = *(const bf16x8*)&Wt[(c0 + j * 16 + lr) * HDIM + ks * 32 + lk];
                a2[j] = __builtin_amdgcn_mfma_f32_16x16x32_bf16(a, b, a2[j], 0, 0, 0);
            }
        }
#pragma unroll
        for (int j = 0; j < 4; ++j) {
            const int col = c0 + j * 16 + lr;
            const float bbv = bb[col];
#pragma unroll
            for (int rg = 0; rg < 4; ++rg)
                opan[(lg * 4 + rg) * XPS + col] = f2bf(fmaxf(a2[j][rg] + bbv, 0.f));
        }
    }
    __syncthreads();

    {   // phase 3: U_p, col-half ch (wave = 2 col-groups), bf16 output
        const ushort* Wt = p ? cW1bT : cW1aT;
        ushort* U        = p ? U2b : U1b;
        const int cb     = ch * 128 + wv * 32;
        const ushort* Ao = opan + lr * XPS + lk;
        f32x4 a2[2];
        a2[0] = (f32x4){0.f, 0.f, 0.f, 0.f};
        a2[1] = (f32x4){0.f, 0.f, 0.f, 0.f};
#pragma unroll
        for (int ks = 0; ks < 8; ++ks) {
            const bf16x8 a = *(const bf16x8*)&Ao[ks * 32];
#pragma unroll
            for (int j = 0; j < 2; ++j) {
                const bf16x8 b = *(const bf16x8*)&Wt[(cb + j * 16 + lr) * HDIM + ks * 32 + lk];
                a2[j] = __builtin_amdgcn_mfma_f32_16x16x32_bf16(a, b, a2[j], 0, 0, 0);
            }
        }
#pragma unroll
        for (int j = 0; j < 2; ++j) {
            const int col = cb + j * 16 + lr;
            const float bbv = (p == 0) ? cb1[col] : 0.f;
#pragma unroll
            for (int rg = 0; rg < 4; ++rg)
                U[(slab + lg * 4 + rg) * HDIM + col] = f2bf(a2[j][rg] + bbv);
        }
    }
}

// ---------------------------------------------------------------------------
// pair_cls: 32x32 tile, 2x2/thread. bf16 LDS panels, f32 w2. (proven)
// ---------------------------------------------------------------------------
__global__ __launch_bounds__(256) void pair_cls(const ushort* __restrict__ U1b,
                                                const ushort* __restrict__ U2b,
                                                const float* __restrict__ W2,
                                                const float* __restrict__ b2,
                                                float* __restrict__ out)
{
    __shared__ __align__(16) ushort u1s[32][264];
    __shared__ __align__(16) ushort u2s[32][264];
    __shared__ __align__(16) float w2s[256];
    const int t  = threadIdx.x;
    const int n0 = blockIdx.y * 32, m0 = blockIdx.x * 32;

#pragma unroll
    for (int u = 0; u < 4; ++u) {
        const int i = t + u * 256;
        const int r = i >> 5, c8 = i & 31;
        *(uint4*)&u1s[r][c8 * 8] = *(const uint4*)&U1b[(n0 + r) * HDIM + c8 * 8];
        *(uint4*)&u2s[r][c8 * 8] = *(const uint4*)&U2b[(m0 + r) * HDIM + c8 * 8];
    }
    if (t < 64) *(float4*)&w2s[t * 4] = *(const float4*)&W2[t * 4];
    __syncthreads();

    const int tx = t & 15, ty = t >> 4;
    const ushort* r0 = &u1s[ty * 2][0];
    const ushort* r1 = &u1s[ty * 2 + 1][0];
    const ushort* c0 = &u2s[tx * 2][0];
    const ushort* c1 = &u2s[tx * 2 + 1][0];
    float acc[2][2] = {};

#define RT(A, B) fmaxf((A) + (B), 0.f)
    for (int h8 = 0; h8 < 32; ++h8) {
        const uint4 A0 = *(const uint4*)&r0[h8 * 8];
        const uint4 A1 = *(const uint4*)&r1[h8 * 8];
        const uint4 B0 = *(const uint4*)&c0[h8 * 8];
        const uint4 B1 = *(const uint4*)&c1[h8 * 8];
        const float4 w0 = *(const float4*)&w2s[h8 * 8];
        const float4 w1 = *(const float4*)&w2s[h8 * 8 + 4];
        const float warr[8] = {w0.x, w0.y, w0.z, w0.w, w1.x, w1.y, w1.z, w1.w};
#pragma unroll
        for (int q = 0; q < 4; ++q) {
            const unsigned a0u = ((const unsigned*)&A0)[q];
            const unsigned a1u = ((const unsigned*)&A1)[q];
            const unsigned b0u = ((const unsigned*)&B0)[q];
            const unsigned b1u = ((const unsigned*)&B1)[q];
            const float a0l = bf_lo(a0u), a0h = bf_hi(a0u);
            const float a1l = bf_lo(a1u), a1h = bf_hi(a1u);
            const float b0l = bf_lo(b0u), b0h = bf_hi(b0u);
            const float b1l = bf_lo(b1u), b1h = bf_hi(b1u);
            const float wl = warr[q * 2], wh = warr[q * 2 + 1];
            acc[0][0] += RT(a0l, b0l) * wl + RT(a0h, b0h) * wh;
            acc[0][1] += RT(a0l, b1l) * wl + RT(a0h, b1h) * wh;
            acc[1][0] += RT(a1l, b0l) * wl + RT(a1h, b0h) * wh;
            acc[1][1] += RT(a1l, b1l) * wl + RT(a1h, b1h) * wh;
        }
    }
#undef RT

    const float bbv = b2[0];
#pragma unroll
    for (int ii = 0; ii < 2; ++ii)
#pragma unroll
        for (int jj = 0; jj < 2; ++jj) {
            const float val = acc[ii][jj] + bbv;
            const int n = n0 + ty * 2 + ii;
            const int m = m0 + tx * 2 + jj;
#pragma unroll
            for (int tl = 0; tl < TLEN; ++tl)
                out[tl * NTOK * NTOK + n * NTOK + m] = val;
        }
}

// ---------------------------------------------------------------------------
extern "C" void kernel_launch(void* const* d_in, const int* in_sizes, int n_in,
                              void* d_out, int out_size, void* d_ws, size_t ws_size,
                              hipStream_t stream)
{
    const float* hs   = (const float*)d_in[0];
    const float* qf   = hs + 5 * NTOK * HDIM;
    const float* alp  = (const float*)d_in[1];
    const float* pl   = alp + 5 * NTOK * 33;
    const float* fc_W = (const float*)d_in[2];
    const float* fc_b = (const float*)d_in[3];
    const float* Wq   = (const float*)d_in[4];
    const float* bq   = (const float*)d_in[5];
    const float* Wk   = (const float*)d_in[6];
    const float* bk   = (const float*)d_in[7];
    const float* Wv   = (const float*)d_in[8];
    const float* bv   = (const float*)d_in[9];
    const float* Wo   = (const float*)d_in[10];
    const float* bo   = (const float*)d_in[11];
    const float* lng  = (const float*)d_in[12];
    const float* lnb  = (const float*)d_in[13];
    const float* m1W  = (const float*)d_in[14];
    const float* m1b  = (const float*)d_in[15];
    const float* m2W  = (const float*)d_in[16];
    const float* m2b  = (const float*)d_in[17];
    const float* cW1  = (const float*)d_in[18];
    const float* cb1  = (const float*)d_in[19];
    const float* cW2  = (const float*)d_in[20];
    const float* cb2  = (const float*)d_in[21];
    float* out = (float*)d_out;

    const int NN  = NTOK * NTOK;
    const int NH_ = NTOK * HDIM;
    float* ws     = (float*)d_ws;
    float* dist   = ws;                       // NN
    float* dwraw  = ws + NN;                  // NN
    float* inv_cs = ws + 2 * NN;              // 512
    float* xa     = ws + 2 * NN + 512;        // NH
    float* xb     = xa + NH_;                 // NH
    ushort* u16   = (ushort*)(xb + NH_);
    ushort* wpk   = u16;                      // 13 * WSZ
    ushort* q16   = wpk + 13 * WSZ;           // NH
    ushort* k16   = q16 + NH_;                // NH
    ushort* vT16  = k16 + NH_;                // NH ([d][m])
    ushort* ao16  = vT16 + NH_;               // NH
    ushort* U1b   = ao16 + NH_;               // NH
    ushort* U2b   = U1b + NH_;                // NH

    // pack1: critical-path weights only (fc + qkv L0)
    PK1 p1;
    p1.w[0] = fc_W; p1.mat[0] = 0;
    p1.w[1] = Wq;   p1.mat[1] = 1;
    p1.w[2] = Wk;   p1.mat[2] = 3;
    p1.w[3] = Wv;   p1.mat[3] = 5;
    p1.wpk = wpk;
    pack1_kernel<<<64, 256, 0, stream>>>(p1);

    // deferred mats packed inside fcqkv
    FQAux aux;
    aux.w[0] = Wq + WSZ;        aux.mat[0] = 2;
    aux.w[1] = Wk + WSZ;        aux.mat[1] = 4;
    aux.w[2] = Wv + WSZ;        aux.mat[2] = 6;
    aux.w[3] = Wo;              aux.mat[3] = 7;
    aux.w[4] = Wo + WSZ;        aux.mat[4] = 8;
    aux.w[5] = m1W;             aux.mat[5] = 9;
    aux.w[6] = m2W;             aux.mat[6] = 10;
    aux.w[7] = cW1;             aux.mat[7] = 11;
    aux.w[8] = cW1 + WSZ;       aux.mat[8] = 12;

    fcqkv<<<344, 256, 0, stream>>>(
        qf, wpk + 0 * WSZ, fc_b,
        wpk + 1 * WSZ, bq, wpk + 3 * WSZ, bk, wpk + 5 * WSZ, bv,
        xa, q16, k16, vT16,
        aux, wpk, pl, dist, dwraw, inv_cs);

    attn_fused<<<128, 512, 0, stream>>>(q16, k16, vT16, dist, dwraw, inv_cs, ao16);

    oprojqkv<<<192, 256, 0, stream>>>(
        ao16, wpk + 7 * WSZ, bo, lng, lnb,
        wpk + 2 * WSZ, bq + HDIM, wpk + 4 * WSZ, bk + HDIM,
        wpk + 6 * WSZ, bv + HDIM,
        xa, xb, q16, k16, vT16);

    attn_fused<<<128, 512, 0, stream>>>(q16, k16, vT16, dist, dwraw, inv_cs, ao16);

    oprojmlpU<<<128, 256, 0, stream>>>(
        ao16, wpk + 8 * WSZ, bo + HDIM, lng + HDIM, lnb + HDIM,
        wpk + 9 * WSZ, m1b, wpk + 10 * WSZ, m2b,
        wpk + 11 * WSZ, cb1, wpk + 12 * WSZ,
        xb, U1b, U2b);

    pair_cls<<<dim3(16, 16), 256, 0, stream>>>(U1b, U2b, cW2, cb2, out);
}